// Round 13
// 213.160 us; speedup vs baseline: 4.3396x; 1.0870x over previous
//
#include <hip/hip_runtime.h>
#include <math.h>

#define NN 4096
#define FF 128
#define HH 32
#define CC 205
#define DD 269
#define LL 512
#define TT 12
#define RR 4
#define KS 16    // k-split for all adj MFMA passes
#define GP 208   // padded gram dim
#define DP 288   // padded D (k) dim for logits MFMA
#define BST 40   // padded LDS row stride (ushorts) for B tiles
#define GTS 224  // transposed-gram row stride / padded K
// padded scalar slots: 0=trSAS 1=adjsq 2=entropy 3=sim 4=embloss 5=sumP2 6=ticket
#define SC(i) ((i) * 32)

typedef __attribute__((ext_vector_type(8))) short bf16x8;
typedef __attribute__((ext_vector_type(4))) float f32x4;
typedef __attribute__((ext_vector_type(8))) unsigned short u16x8;

// ---------------- helpers ----------------
__device__ __forceinline__ float wave_sum(float v) {
#pragma unroll
  for (int o = 32; o > 0; o >>= 1) v += __shfl_xor(v, o, 64);
  return v;
}
__device__ __forceinline__ float wave_max(float v) {
#pragma unroll
  for (int o = 32; o > 0; o >>= 1) v = fmaxf(v, __shfl_xor(v, o, 64));
  return v;
}
__device__ __forceinline__ unsigned short f2bf(float x) {  // RNE
  union { float f; unsigned u; } v; v.f = x;
  unsigned r = v.u + 0x7FFFu + ((v.u >> 16) & 1u);
  return (unsigned short)(r >> 16);
}

// ---------------- fused prep: [0..127] conv1 dual projection; [128..255] xn/xnR/xnB; all: Wl1T ----------------
__global__ __launch_bounds__(256) void k_prep(const float* __restrict__ x,
                                              const float* __restrict__ W1r,
                                              const float* __restrict__ W1root,
                                              const float* __restrict__ Wl1,
                                              unsigned short* __restrict__ mB,
                                              float* __restrict__ rootb,
                                              float* __restrict__ xn,
                                              unsigned short* __restrict__ xnR,
                                              unsigned short* __restrict__ xnB,
                                              unsigned short* __restrict__ Wl1T) {
  __shared__ float sX[32][132];
  __shared__ unsigned short sT[32][34];
  __shared__ unsigned short sT2[FF][34];
  const int tid = threadIdx.x;
  {
    const int i = blockIdx.x * 256 + tid;
    if (i < GP * DP) {
      const int c = i / DP, k = i - c * DP;
      Wl1T[i] = (c < CC && k < DD) ? f2bf(Wl1[(size_t)k * CC + c]) : (unsigned short)0;
    }
  }
  if (blockIdx.x < 128) {
    const int kb = blockIdx.x;
    for (int p = tid; p < 1024; p += 256) {
      const int node = p >> 5, c4 = p & 31;
      const float4 v = *reinterpret_cast<const float4*>(&x[((size_t)(kb * 32 + node)) * FF + c4 * 4]);
      sX[node][c4 * 4 + 0] = v.x; sX[node][c4 * 4 + 1] = v.y;
      sX[node][c4 * 4 + 2] = v.z; sX[node][c4 * 4 + 3] = v.w;
    }
    __syncthreads();
    const int c = tid & 31, g = tid >> 5;
    float a1[4] = {0.f, 0.f, 0.f, 0.f}, a2[4] = {0.f, 0.f, 0.f, 0.f};
    for (int k = 0; k < FF; ++k) {
      const float w1 = W1r[k * HH + c];
      const float w2 = W1root[k * HH + c];
#pragma unroll
      for (int ni = 0; ni < 4; ++ni) {
        const float av = sX[g * 4 + ni][k];
        a1[ni] = fmaf(av, w1, a1[ni]);
        a2[ni] = fmaf(av, w2, a2[ni]);
      }
    }
#pragma unroll
    for (int ni = 0; ni < 4; ++ni) {
      rootb[((size_t)kb * 32 + g * 4 + ni) * HH + c] = a2[ni];
      sT[c][g * 4 + ni] = f2bf(a1[ni]);
    }
    __syncthreads();
    if (tid < 128) {
      const int row = tid >> 2, seg = tid & 3;
      u16x8 v;
#pragma unroll
      for (int j = 0; j < 8; ++j) v[j] = sT[row][seg * 8 + j];
      *reinterpret_cast<u16x8*>(&mB[((size_t)kb * 32 + row) * 32 + seg * 8]) = v;
    }
  } else {
    const int kb = blockIdx.x - 128;
    const int lane = tid & 63;
    const int w = tid >> 6;
#pragma unroll
    for (int i = 0; i < 8; ++i) {
      const int node = w * 8 + i;
      const int row = kb * 32 + node;
      const float v0 = x[(size_t)row * FF + lane];
      const float v1 = x[(size_t)row * FF + 64 + lane];
      const float ss = wave_sum(v0 * v0 + v1 * v1);
      const float n = fmaxf(sqrtf(ss), 1e-8f);
      const float a = v0 / n, b = v1 / n;
      xn[(size_t)row * FF + lane] = a;
      xn[(size_t)row * FF + 64 + lane] = b;
      xnR[(size_t)row * FF + lane] = f2bf(a);
      xnR[(size_t)row * FF + 64 + lane] = f2bf(b);
      sT2[lane][node] = f2bf(a);
      sT2[64 + lane][node] = f2bf(b);
    }
    __syncthreads();
    const int rowc = tid >> 1, seg = (tid & 1) * 16;
    if (rowc < FF) {
      u16x8 a, b;
#pragma unroll
      for (int j = 0; j < 8; ++j) { a[j] = sT2[rowc][seg + j]; b[j] = sT2[rowc][seg + 8 + j]; }
      *reinterpret_cast<u16x8*>(&xnB[((size_t)kb * GP + rowc) * 32 + seg]) = a;
      *reinterpret_cast<u16x8*>(&xnB[((size_t)kb * GP + rowc) * 32 + seg + 8]) = b;
    }
  }
}

// ---------------- FUSED conv1: fp32 adj -> bf16 tiled adj_t + sum(adj^2) + MFMA ----------------
__global__ __launch_bounds__(256) void k_conv1f(const float* __restrict__ adj,
                                                unsigned short* __restrict__ adj_t,
                                                const unsigned short* __restrict__ mB,
                                                float* __restrict__ part,
                                                float* __restrict__ scalars) {
  __shared__ unsigned short sA[64][264];
  __shared__ float red[4];
  const int tid = threadIdx.x;
  const int rbase_blk = blockIdx.x * 64;
  const int kbase = blockIdx.y * 256;
  const int rb0 = blockIdx.x * 4;
  const int kb0 = blockIdx.y * 8;
  const int lane = tid & 63;
  const int w = tid >> 6;
  const int l15 = lane & 15;
  const int kgrp = (lane >> 4) * 8;
  bf16x8 bb0[8], bb1[8];
#pragma unroll
  for (int kt = 0; kt < 8; ++kt) {
    const size_t boff = ((size_t)(kb0 + kt) * 32) * 32;
    bb0[kt] = *reinterpret_cast<const bf16x8*>(&mB[boff + (size_t)l15 * 32 + kgrp]);
    bb1[kt] = *reinterpret_cast<const bf16x8*>(&mB[boff + (size_t)(16 + l15) * 32 + kgrp]);
  }
  float adjsq = 0.f;
#pragma unroll
  for (int i = 0; i < 16; ++i) {
    const int fi = i * 256 + tid;
    const int r = fi >> 6;
    const int c4 = fi & 63;
    const size_t goff = (size_t)(rbase_blk + r) * NN + kbase + c4 * 4;
    const float4 v = *reinterpret_cast<const float4*>(&adj[goff]);
    adjsq += v.x * v.x + v.y * v.y + v.z * v.z + v.w * v.w;
    ushort4 h;
    h.x = f2bf(v.x); h.y = f2bf(v.y); h.z = f2bf(v.z); h.w = f2bf(v.w);
    const size_t toff = ((size_t)(rb0 + (r >> 4)) * (NN / 32) + kb0 + (c4 >> 3)) * 512 +
                        (r & 15) * 32 + (c4 & 7) * 4;
    *reinterpret_cast<ushort4*>(&adj_t[toff]) = h;
    *reinterpret_cast<ushort4*>(&sA[r][c4 * 4]) = h;
  }
  __syncthreads();
  const int rloc = w * 16 + l15;
  f32x4 acc0 = {0.f, 0.f, 0.f, 0.f}, acc1 = {0.f, 0.f, 0.f, 0.f};
#pragma unroll
  for (int k0 = 0; k0 < 256; k0 += 32) {
    const bf16x8 a = *reinterpret_cast<const bf16x8*>(&sA[rloc][k0 + kgrp]);
    acc0 = __builtin_amdgcn_mfma_f32_16x16x32_bf16(a, bb0[k0 >> 5], acc0, 0, 0, 0);
    acc1 = __builtin_amdgcn_mfma_f32_16x16x32_bf16(a, bb1[k0 >> 5], acc1, 0, 0, 0);
  }
  float* pp = part + (size_t)blockIdx.y * (NN * HH);
  const int rout = rbase_blk + w * 16 + (lane >> 4) * 4;
#pragma unroll
  for (int r = 0; r < 4; ++r) {
    pp[(size_t)(rout + r) * HH + l15] = acc0[r];
    pp[(size_t)(rout + r) * HH + 16 + l15] = acc1[r];
  }
  adjsq = wave_sum(adjsq);
  if (lane == 0) red[w] = adjsq;
  __syncthreads();
  if (tid == 0) atomicAdd(&scalars[SC(1)], red[0] + red[1] + red[2] + red[3]);
}

// ---------------- MFMA adj pass (register-hoisted) ----------------
__global__ __launch_bounds__(256) void k_adjmm(const unsigned short* __restrict__ adj_t,
                                               const unsigned short* __restrict__ mB,
                                               float* __restrict__ part) {
  const int tid = threadIdx.x;
  const int lane = tid & 63;
  const int w = tid >> 6;
  const int rb = blockIdx.x * 4 + w;
  const int kb0 = blockIdx.y * 8;
  const int l15 = lane & 15;
  const int kgrp = (lane >> 4) * 8;
  bf16x8 a[8], b0[8], b1[8];
#pragma unroll
  for (int kt = 0; kt < 8; ++kt) {
    const size_t aoff = ((size_t)rb * (NN / 32) + kb0 + kt) * 512;
    const size_t boff = ((size_t)(kb0 + kt) * 32) * 32;
    a[kt] = *reinterpret_cast<const bf16x8*>(&adj_t[aoff + l15 * 32 + kgrp]);
    b0[kt] = *reinterpret_cast<const bf16x8*>(&mB[boff + (size_t)l15 * 32 + kgrp]);
    b1[kt] = *reinterpret_cast<const bf16x8*>(&mB[boff + (size_t)(16 + l15) * 32 + kgrp]);
  }
  f32x4 acc0 = {0.f, 0.f, 0.f, 0.f}, acc1 = {0.f, 0.f, 0.f, 0.f};
#pragma unroll
  for (int kt = 0; kt < 8; ++kt) {
    acc0 = __builtin_amdgcn_mfma_f32_16x16x32_bf16(a[kt], b0[kt], acc0, 0, 0, 0);
    acc1 = __builtin_amdgcn_mfma_f32_16x16x32_bf16(a[kt], b1[kt], acc1, 0, 0, 0);
  }
  float* pp = part + (size_t)blockIdx.y * (NN * HH);
  const int rout = rb * 16 + (lane >> 4) * 4;
#pragma unroll
  for (int r = 0; r < 4; ++r) {
    pp[(size_t)(rout + r) * HH + l15] = acc0[r];
    pp[(size_t)(rout + r) * HH + 16 + l15] = acc1[r];
  }
}

// ---------------- conv epilogue (32-wide) ----------------
__global__ __launch_bounds__(256) void k_epi32(const float* __restrict__ part,
                                               const float* __restrict__ bias,
                                               const float* __restrict__ root,
                                               float* __restrict__ t,
                                               float* __restrict__ colsum,
                                               float* __restrict__ colsq) {
  __shared__ float ls[HH], lq[HH];
  const int tid = threadIdx.x;
  const int idx = blockIdx.x * 256 + tid;
  const int c = idx & (HH - 1);
  if (tid < HH) { ls[tid] = 0.f; lq[tid] = 0.f; }
  __syncthreads();
  float s = bias[c] + root[idx];
#pragma unroll
  for (int sp = 0; sp < KS; ++sp) s += part[(size_t)sp * (NN * HH) + idx];
  s = fmaxf(s, 0.f);
  t[idx] = s;
  atomicAdd(&ls[c], s);
  atomicAdd(&lq[c], s * s);
  __syncthreads();
  if (tid < HH) {
    atomicAdd(&colsum[tid * 16], ls[tid]);
    atomicAdd(&colsq[tid * 16], lq[tid]);
  }
}

// ---------------- FUSED: BN1 apply (inline stats) + emb write + conv2 dual projection ----------------
// grid 128; block = 32 nodes
__global__ __launch_bounds__(256) void k_bnproj(const float* __restrict__ t,
                                                const float* __restrict__ colsum,
                                                const float* __restrict__ colsq,
                                                const float* __restrict__ g,
                                                const float* __restrict__ be,
                                                const float* __restrict__ W2r,
                                                const float* __restrict__ W2root,
                                                unsigned short* __restrict__ mB,
                                                float* __restrict__ rootb,
                                                float* __restrict__ emb) {
  __shared__ float sXf[32][33];
  __shared__ unsigned short sT[32][34];
  const int tid = threadIdx.x;
  const int kb = blockIdx.x;
  const int c = tid & 31, gq = tid >> 5;
  const float m = colsum[c * 16] * (1.f / NN);
  const float var = fmaxf(colsq[c * 16] * (1.f / NN) - m * m, 0.f);
  const float Ac = g[c] / sqrtf(var + 1e-5f);
  const float Bc = be[c] - m * Ac;
#pragma unroll
  for (int ni = 0; ni < 4; ++ni) {
    const int n = kb * 32 + gq * 4 + ni;
    const float v = fmaf(Ac, t[(size_t)n * HH + c], Bc);
    emb[(size_t)n * DD + c] = v;
    sXf[gq * 4 + ni][c] = v;
  }
  __syncthreads();
  float a1[4] = {0.f, 0.f, 0.f, 0.f}, a2[4] = {0.f, 0.f, 0.f, 0.f};
  for (int k = 0; k < HH; ++k) {
    const float w1 = W2r[k * HH + c];
    const float w2 = W2root[k * HH + c];
#pragma unroll
    for (int ni = 0; ni < 4; ++ni) {
      const float av = sXf[gq * 4 + ni][k];
      a1[ni] = fmaf(av, w1, a1[ni]);
      a2[ni] = fmaf(av, w2, a2[ni]);
    }
  }
#pragma unroll
  for (int ni = 0; ni < 4; ++ni) {
    rootb[((size_t)kb * 32 + gq * 4 + ni) * HH + c] = a2[ni];
    sT[c][gq * 4 + ni] = f2bf(a1[ni]);
  }
  __syncthreads();
  if (tid < 128) {
    const int row = tid >> 2, seg = tid & 3;
    u16x8 v;
#pragma unroll
    for (int j = 0; j < 8; ++j) v[j] = sT[row][seg * 8 + j];
    *reinterpret_cast<u16x8*>(&mB[((size_t)kb * 32 + row) * 32 + seg * 8]) = v;
  }
}

// ---------------- bn apply conv2 (inline stats) + x2 + emb + tiled x2B ----------------
__global__ __launch_bounds__(256) void k_bnapply32(const float* __restrict__ t,
                                                   const float* __restrict__ colsum,
                                                   const float* __restrict__ colsq,
                                                   const float* __restrict__ g,
                                                   const float* __restrict__ be,
                                                   float* __restrict__ xo,
                                                   float* __restrict__ emb, int embOff,
                                                   unsigned short* __restrict__ xB) {
  __shared__ unsigned short sT[32][34];
  const int tid = threadIdx.x;
  const int kb = blockIdx.x;
  const int c = tid & 31, gq = tid >> 5;
  const float m = colsum[c * 16] * (1.f / NN);
  const float var = fmaxf(colsq[c * 16] * (1.f / NN) - m * m, 0.f);
  const float Ac = g[c] / sqrtf(var + 1e-5f);
  const float Bc = be[c] - m * Ac;
#pragma unroll
  for (int ni = 0; ni < 4; ++ni) {
    const int n = kb * 32 + gq * 4 + ni;
    const float v = fmaf(Ac, t[(size_t)n * HH + c], Bc);
    xo[(size_t)n * HH + c] = v;
    emb[(size_t)n * DD + embOff + c] = v;
    sT[c][gq * 4 + ni] = f2bf(v);
  }
  __syncthreads();
  if (tid < 128) {
    const int row = tid >> 2, seg = tid & 3;
    u16x8 o;
#pragma unroll
    for (int j = 0; j < 8; ++j) o[j] = sT[row][seg * 8 + j];
    *reinterpret_cast<u16x8*>(&xB[((size_t)kb * 32 + row) * 32 + seg * 8]) = o;
  }
}

// ---------------- conv3 epilogue ----------------
__global__ __launch_bounds__(256) void k_epi3(const float* __restrict__ part,
                                              const float* __restrict__ W3r,
                                              const float* __restrict__ b3,
                                              const float* __restrict__ x2,
                                              const float* __restrict__ W3root,
                                              float* __restrict__ t3,
                                              float* __restrict__ colsum,
                                              float* __restrict__ colsq) {
  __shared__ float z[16][33];
  __shared__ float xr[16][33];
  const int row0 = blockIdx.x * 16;
  for (int s = threadIdx.x; s < 16 * 32; s += 256) {
    const int r = s >> 5, k = s & 31;
    float a = 0.f;
#pragma unroll
    for (int sp = 0; sp < KS; ++sp)
      a += part[(size_t)sp * (NN * HH) + (size_t)(row0 + r) * HH + k];
    z[r][k] = a;
    xr[r][k] = x2[(size_t)(row0 + r) * HH + k];
  }
  __syncthreads();
  const int c = threadIdx.x;
  if (c >= CC) return;
  float acc[16];
  const float bb = b3[c];
#pragma unroll
  for (int r = 0; r < 16; ++r) acc[r] = bb;
  for (int k = 0; k < 32; ++k) {
    const float w1 = W3r[k * CC + c];
    const float w2 = W3root[k * CC + c];
#pragma unroll
    for (int r = 0; r < 16; ++r) acc[r] += z[r][k] * w1 + xr[r][k] * w2;
  }
  float lsm = 0.f, lqm = 0.f;
#pragma unroll
  for (int r = 0; r < 16; ++r) {
    const float v = fmaxf(acc[r], 0.f);
    t3[(size_t)(row0 + r) * CC + c] = v;
    lsm += v;
    lqm += v * v;
  }
  atomicAdd(&colsum[c * 16], lsm);
  atomicAdd(&colsq[c * 16], lqm);
}

// ---------------- fused head: BN3 inline + emb write + MFMA logits + softmax ----------------
// grid NN/16; 16 rows per block; 4 waves
__global__ __launch_bounds__(256) void k_head(float* __restrict__ emb,
                                              const float* __restrict__ t3,
                                              const float* __restrict__ colsum3,
                                              const float* __restrict__ colsq3,
                                              const float* __restrict__ g3,
                                              const float* __restrict__ be3,
                                              const unsigned short* __restrict__ Wl1T,
                                              const float* __restrict__ bl1,
                                              float* __restrict__ s1,
                                              float* __restrict__ sn,
                                              unsigned short* __restrict__ s1B,
                                              unsigned short* __restrict__ snB,
                                              unsigned short* __restrict__ snR,
                                              float* __restrict__ scalars) {
  __shared__ unsigned short sA[16][296];
  __shared__ float lg[16][212];
  __shared__ unsigned short sTa[16][212];
  __shared__ unsigned short sTb[16][212];
  __shared__ float redE[4];
  const int tid = threadIdx.x;
  const int row0 = blockIdx.x * 16;
  // stage emb: cols 0..63 read; cols 64..268 = BN3(t3) computed + written back; pad zero
  for (int p = tid; p < 16 * 36; p += 256) {
    const int r = p / 36, ch = p - r * 36;
    const int row = row0 + r;
#pragma unroll
    for (int j = 0; j < 8; ++j) {
      const int d = ch * 8 + j;
      float v;
      if (d < 2 * HH) {
        v = emb[(size_t)row * DD + d];
      } else if (d < DD) {
        const int c3 = d - 2 * HH;
        const float m = colsum3[c3 * 16] * (1.f / NN);
        const float var = fmaxf(colsq3[c3 * 16] * (1.f / NN) - m * m, 0.f);
        const float Ac = g3[c3] / sqrtf(var + 1e-5f);
        const float Bc = be3[c3] - m * Ac;
        v = fmaf(Ac, t3[(size_t)row * CC + c3], Bc);
        emb[(size_t)row * DD + d] = v;
      } else {
        v = 0.f;
      }
      sA[r][d] = f2bf(v);
    }
  }
  __syncthreads();
  const int lane = tid & 63;
  const int w = tid >> 6;
  const int l15 = lane & 15;
  const int kgrp = (lane >> 4) * 8;
  {
    f32x4 acc[4];
#pragma unroll
    for (int i = 0; i < 4; ++i) acc[i] = (f32x4){0.f, 0.f, 0.f, 0.f};
#pragma unroll
    for (int i = 0; i < 4; ++i) {
      const int ct = w + i * 4;
      if (ct < 13) {
        const size_t brow = (size_t)(ct * 16 + l15) * DP;
#pragma unroll
        for (int k0 = 0; k0 < DP; k0 += 32) {
          const bf16x8 a = *reinterpret_cast<const bf16x8*>(&sA[l15][k0 + kgrp]);
          const bf16x8 b = *reinterpret_cast<const bf16x8*>(&Wl1T[brow + k0 + kgrp]);
          acc[i] = __builtin_amdgcn_mfma_f32_16x16x32_bf16(a, b, acc[i], 0, 0, 0);
        }
      }
    }
    const int lrow = (lane >> 4) * 4;
#pragma unroll
    for (int i = 0; i < 4; ++i) {
      const int ct = w + i * 4;
      if (ct < 13) {
#pragma unroll
        for (int r = 0; r < 4; ++r) lg[lrow + r][ct * 16 + l15] = acc[i][r];
      }
    }
  }
  __syncthreads();
  const int r0 = w * 4;
  const int c0 = lane * 4;
  const bool active = (c0 < GP);
  float bl[4];
#pragma unroll
  for (int j = 0; j < 4; ++j) bl[j] = (c0 + j < CC) ? bl1[c0 + j] : 0.f;
  float ent_acc = 0.f;
#pragma unroll
  for (int r = 0; r < 4; ++r) {
    const int lr = r0 + r;
    const int row = row0 + lr;
    float lgv[4] = {0.f, 0.f, 0.f, 0.f};
    if (active) {
#pragma unroll
      for (int j = 0; j < 4; ++j) lgv[j] = lg[lr][c0 + j];
    }
    float v[4];
    float ml = -1e30f;
#pragma unroll
    for (int j = 0; j < 4; ++j) {
      const int c = c0 + j;
      v[j] = (c < CC) ? fmaxf(lgv[j] + bl[j], 0.f) : -1e30f;
      ml = fmaxf(ml, v[j]);
    }
    const float m = wave_max(ml);
    float e[4];
    float sl = 0.f;
#pragma unroll
    for (int j = 0; j < 4; ++j) {
      const int c = c0 + j;
      e[j] = (c < CC) ? __expf(v[j] - m) : 0.f;
      sl += e[j];
    }
    const float S = wave_sum(sl);
    const float invS = 1.f / S;
    float p[4];
    float ql = 0.f;
#pragma unroll
    for (int j = 0; j < 4; ++j) {
      p[j] = e[j] * invS;
      ql += p[j] * p[j];
    }
    const float q = wave_sum(ql);
    const float inv = 1.f / fmaxf(sqrtf(q), 1e-8f);
    float m2l = -1e30f;
#pragma unroll
    for (int j = 0; j < 4; ++j) {
      const int c = c0 + j;
      if (c < CC) {
        s1[(size_t)row * CC + c] = p[j];
        sn[(size_t)row * CC + c] = p[j] * inv;
        m2l = fmaxf(m2l, p[j]);
      }
    }
    if (active) {
#pragma unroll
      for (int j = 0; j < 4; ++j) {
        const int c = c0 + j;
        const bool ok = (c < CC);
        sTa[lr][c] = ok ? f2bf(p[j]) : (unsigned short)0;
        sTb[lr][c] = ok ? f2bf(p[j] * inv) : (unsigned short)0;
      }
    }
    if (c0 < GTS) {
      ushort4 o;
      o.x = (c0 + 0 < CC) ? f2bf(p[0] * inv) : (unsigned short)0;
      o.y = (c0 + 1 < CC) ? f2bf(p[1] * inv) : (unsigned short)0;
      o.z = (c0 + 2 < CC) ? f2bf(p[2] * inv) : (unsigned short)0;
      o.w = (c0 + 3 < CC) ? f2bf(p[3] * inv) : (unsigned short)0;
      *reinterpret_cast<ushort4*>(&snR[(size_t)row * GTS + c0]) = o;
    }
    const float m2 = wave_max(m2l);
    float e2[4];
    float s2l = 0.f;
#pragma unroll
    for (int j = 0; j < 4; ++j) {
      const int c = c0 + j;
      e2[j] = (c < CC) ? __expf(p[j] - m2) : 0.f;
      s2l += e2[j];
    }
    const float S2 = wave_sum(s2l);
    const float invS2 = 1.f / S2;
    float tl = 0.f;
#pragma unroll
    for (int j = 0; j < 4; ++j) {
      const int c = c0 + j;
      if (c < CC) {
        const float sp = e2[j] * invS2;
        tl -= sp * logf(sp + 1e-15f);
      }
    }
    ent_acc += tl;
  }
  ent_acc = wave_sum(ent_acc);
  if (lane == 0) redE[w] = ent_acc;
  __syncthreads();
  if (tid == 0) atomicAdd(&scalars[SC(2)], redE[0] + redE[1] + redE[2] + redE[3]);
  if (tid < GP) {
    const int kb = row0 >> 5, no = row0 & 31;
    u16x8 oa0, ob0, oa1, ob1;
#pragma unroll
    for (int r = 0; r < 8; ++r) {
      oa0[r] = sTa[r][tid]; ob0[r] = sTb[r][tid];
      oa1[r] = sTa[8 + r][tid]; ob1[r] = sTb[8 + r][tid];
    }
    *reinterpret_cast<u16x8*>(&s1B[((size_t)kb * GP + tid) * 32 + no]) = oa0;
    *reinterpret_cast<u16x8*>(&s1B[((size_t)kb * GP + tid) * 32 + no + 8]) = oa1;
    *reinterpret_cast<u16x8*>(&snB[((size_t)kb * GP + tid) * 32 + no]) = ob0;
    *reinterpret_cast<u16x8*>(&snB[((size_t)kb * GP + tid) * 32 + no + 8]) = ob1;
  }
}

// ---------------- merged tail: [0..511] norm pass (512thr); [512..1187] Grams (8-wave k-split) ----------------
__global__ __launch_bounds__(512) void k_tail(const unsigned short* __restrict__ adj_t,
                                              const unsigned short* __restrict__ s1B,
                                              const float* __restrict__ s1,
                                              const unsigned short* __restrict__ xnB,
                                              const unsigned short* __restrict__ snB,
                                              unsigned short* __restrict__ GT0,
                                              unsigned short* __restrict__ GxsT,
                                              unsigned short* __restrict__ GsT,
                                              float* __restrict__ scalars) {
  const int tid = threadIdx.x;
  const int lane = tid & 63;
  const int w = tid >> 6;
  const int l15 = lane & 15;
  const int kgrp = (lane >> 4) * 8;
  if (blockIdx.x < 512) {
    // ===== norm: scalars[0] += sum((adj@S1) .* s1) =====
    __shared__ unsigned short sB[2][13][16][BST];
    __shared__ float red[8];
    const int bx = blockIdx.x & 31;
    const int ky = blockIdx.x >> 5;
    const int rb = bx * 8 + w;
    const int kb0 = ky * 8;
    const int g = lane >> 4;
    const int p0 = tid;
    const int ct0 = p0 >> 6, rr0 = (p0 >> 2) & 15, sg0 = (p0 & 3) * 8;
    const int p1 = tid + 512;
    const bool v1 = (p1 < 832);
    const int ct1 = p1 >> 6, rr1 = (p1 >> 2) & 15, sg1 = (p1 & 3) * 8;
    f32x4 acc[13];
#pragma unroll
    for (int ct = 0; ct < 13; ++ct) acc[ct] = (f32x4){0.f, 0.f, 0.f, 0.f};
    u16x8 st0, st1;
    st0 = *reinterpret_cast<const u16x8*>(&s1B[((size_t)kb0 * GP + ct0 * 16 + rr0) * 32 + sg0]);
    if (v1) st1 = *reinterpret_cast<const u16x8*>(&s1B[((size_t)kb0 * GP + ct1 * 16 + rr1) * 32 + sg1]);
    *reinterpret_cast<u16x8*>(&sB[0][ct0][rr0][sg0]) = st0;
    if (v1) *reinterpret_cast<u16x8*>(&sB[0][ct1][rr1][sg1]) = st1;
    __syncthreads();
    bf16x8 a = *reinterpret_cast<const bf16x8*>(
        &adj_t[((size_t)rb * (NN / 32) + kb0) * 512 + l15 * 32 + kgrp]);
    for (int kt = 0; kt < 8; ++kt) {
      const int cur = kt & 1;
      if (kt < 7) {
        const size_t kb = kb0 + kt + 1;
        st0 = *reinterpret_cast<const u16x8*>(&s1B[(kb * GP + ct0 * 16 + rr0) * 32 + sg0]);
        if (v1) st1 = *reinterpret_cast<const u16x8*>(&s1B[(kb * GP + ct1 * 16 + rr1) * 32 + sg1]);
      }
      bf16x8 a_next = a;
      if (kt < 7)
        a_next = *reinterpret_cast<const bf16x8*>(
            &adj_t[((size_t)rb * (NN / 32) + kb0 + kt + 1) * 512 + l15 * 32 + kgrp]);
#pragma unroll
      for (int ct = 0; ct < 13; ++ct) {
        const bf16x8 b = *reinterpret_cast<const bf16x8*>(&sB[cur][ct][l15][kgrp]);
        acc[ct] = __builtin_amdgcn_mfma_f32_16x16x32_bf16(a, b, acc[ct], 0, 0, 0);
      }
      if (kt < 7) {
        *reinterpret_cast<u16x8*>(&sB[cur ^ 1][ct0][rr0][sg0]) = st0;
        if (v1) *reinterpret_cast<u16x8*>(&sB[cur ^ 1][ct1][rr1][sg1]) = st1;
      }
      __syncthreads();
      a = a_next;
    }
    const int rout = rb * 16 + g * 4;
    float sc = 0.f;
#pragma unroll
    for (int ct = 0; ct < 13; ++ct) {
      const int col = ct * 16 + l15;
      if (col < CC) {
#pragma unroll
        for (int r = 0; r < 4; ++r)
          sc = fmaf(acc[ct][r], s1[(size_t)(rout + r) * CC + col], sc);
      }
    }
    sc = wave_sum(sc);
    if (lane == 0) red[w] = sc;
    __syncthreads();
    if (tid == 0) {
      float s = 0.f;
#pragma unroll
      for (int i = 0; i < 8; ++i) s += red[i];
      atomicAdd(&scalars[SC(0)], s);
    }
  } else {
    // ===== Grams: GT bf16 outputs; gid==3 reduces sum(Gs0^2) =====
    __shared__ float redg[8][16][17];
    __shared__ float redq[8];
    const int gb = blockIdx.x - 512;
    const int gid = gb / 169;
    const int rem = gb - gid * 169;
    const int tp = (rem % 13) * 16;
    const int tq = (rem / 13) * 16;
    const unsigned short *PT, *QT;
    unsigned short* GTout = nullptr;
    if (gid == 0)      { PT = xnB; QT = xnB; GTout = GT0;  if (tp >= FF || tq >= FF) return; }
    else if (gid == 1) { PT = xnB; QT = snB; GTout = GxsT; if (tp >= FF) return; }
    else if (gid == 2) { PT = snB; QT = snB; GTout = GsT; }
    else               { PT = s1B; QT = s1B; }
    f32x4 acc = {0.f, 0.f, 0.f, 0.f};
#pragma unroll 4
    for (int kt = 0; kt < 16; ++kt) {
      const int kb = w * 16 + kt;
      const bf16x8 a = *reinterpret_cast<const bf16x8*>(&PT[((size_t)kb * GP + tp + l15) * 32 + kgrp]);
      const bf16x8 b = *reinterpret_cast<const bf16x8*>(&QT[((size_t)kb * GP + tq + l15) * 32 + kgrp]);
      acc = __builtin_amdgcn_mfma_f32_16x16x32_bf16(a, b, acc, 0, 0, 0);
    }
    const int crow = (lane >> 4) * 4;
#pragma unroll
    for (int r = 0; r < 4; ++r) redg[w][crow + r][l15] = acc[r];
    __syncthreads();
    const int rr = tid >> 4, cc = tid & 15;
    if (gid == 3) {
      float q = 0.f;
      if (tid < 256) {
        float v = 0.f;
#pragma unroll
        for (int i = 0; i < 8; ++i) v += redg[i][rr][cc];
        q = v * v;
      }
      q = wave_sum(q);
      if (lane == 0) redq[w] = q;
      __syncthreads();
      if (tid == 0) {
        float s = 0.f;
#pragma unroll
        for (int i = 0; i < 8; ++i) s += redq[i];
        atomicAdd(&scalars[SC(5)], s);
      }
    } else {
      if (tid < 256) {
        float vt = 0.f;
#pragma unroll
        for (int i = 0; i < 8; ++i) vt += redg[i][cc][rr];
        GTout[(size_t)(tq + rr) * GTS + (tp + cc)] = f2bf(vt);
      }
    }
  }
}

// ---------------- fused bilinear forms + sim: H kept in LDS, sim contracted in-kernel ----------------
// grid NN/16, 256 thr
__global__ __launch_bounds__(256) void k_rowsim(const unsigned short* __restrict__ xnR,
                                                const unsigned short* __restrict__ snR,
                                                const unsigned short* __restrict__ GT0,
                                                const unsigned short* __restrict__ GxsT,
                                                const unsigned short* __restrict__ GsT,
                                                const float* __restrict__ xn,
                                                const float* __restrict__ sn,
                                                float* __restrict__ scalars) {
  __shared__ unsigned short sX[16][136];
  __shared__ unsigned short sS[16][232];
  __shared__ float sH1[16][132];
  __shared__ float sU[16][212];
  __shared__ float sH2[16][212];
  __shared__ float redb[4];
  const int tid = threadIdx.x;
  const int row0 = blockIdx.x * 16;
  for (int p = tid; p < 16 * 16; p += 256) {
    const int r = p >> 4, ch = p & 15;
    *reinterpret_cast<u16x8*>(&sX[r][ch * 8]) =
        *reinterpret_cast<const u16x8*>(&xnR[(size_t)(row0 + r) * FF + ch * 8]);
  }
  for (int p = tid; p < 16 * 28; p += 256) {
    const int r = p / 28, ch = p - r * 28;
    *reinterpret_cast<u16x8*>(&sS[r][ch * 8]) =
        *reinterpret_cast<const u16x8*>(&snR[(size_t)(row0 + r) * GTS + ch * 8]);
  }
  __syncthreads();
  const int lane = tid & 63;
  const int w = tid >> 6;
  const int l15 = lane & 15;
  const int kgrp = (lane >> 4) * 8;
  const int lrow = (lane >> 4) * 4;
  // H1 = xn @ G (8 col-tiles, K=128)
#pragma unroll
  for (int i = 0; i < 2; ++i) {
    const int ct = w + i * 4;
    f32x4 acc = {0.f, 0.f, 0.f, 0.f};
    const size_t brow = (size_t)(ct * 16 + l15) * GTS;
#pragma unroll
    for (int k0 = 0; k0 < FF; k0 += 32) {
      const bf16x8 a = *reinterpret_cast<const bf16x8*>(&sX[l15][k0 + kgrp]);
      const bf16x8 b = *reinterpret_cast<const bf16x8*>(&GT0[brow + k0 + kgrp]);
      acc = __builtin_amdgcn_mfma_f32_16x16x32_bf16(a, b, acc, 0, 0, 0);
    }
#pragma unroll
    for (int r = 0; r < 4; ++r) sH1[lrow + r][ct * 16 + l15] = acc[r];
  }
  // Uu = xn @ Gxs (13 col-tiles, K=128)
#pragma unroll
  for (int i = 0; i < 4; ++i) {
    const int ct = w + i * 4;
    if (ct < 13) {
      f32x4 acc = {0.f, 0.f, 0.f, 0.f};
      const size_t brow = (size_t)(ct * 16 + l15) * GTS;
#pragma unroll
      for (int k0 = 0; k0 < FF; k0 += 32) {
        const bf16x8 a = *reinterpret_cast<const bf16x8*>(&sX[l15][k0 + kgrp]);
        const bf16x8 b = *reinterpret_cast<const bf16x8*>(&GxsT[brow + k0 + kgrp]);
        acc = __builtin_amdgcn_mfma_f32_16x16x32_bf16(a, b, acc, 0, 0, 0);
      }
#pragma unroll
      for (int r = 0; r < 4; ++r) sU[lrow + r][ct * 16 + l15] = acc[r];
    }
  }
  // H2 = sn @ Gs (13 col-tiles, K=224)
#pragma unroll
  for (int i = 0; i < 4; ++i) {
    const int ct = w + i * 4;
    if (ct < 13) {
      f32x4 acc = {0.f, 0.f, 0.f, 0.f};
      const size_t brow = (size_t)(ct * 16 + l15) * GTS;
#pragma unroll
      for (int k0 = 0; k0 < GTS; k0 += 32) {
        const bf16x8 a = *reinterpret_cast<const bf16x8*>(&sS[l15][k0 + kgrp]);
        const bf16x8 b = *reinterpret_cast<const bf16x8*>(&GsT[brow + k0 + kgrp]);
        acc = __builtin_amdgcn_mfma_f32_16x16x32_bf16(a, b, acc, 0, 0, 0);
      }
#pragma unroll
      for (int r = 0; r < 4; ++r) sH2[lrow + r][ct * 16 + l15] = acc[r];
    }
  }
  __syncthreads();
  // sim epilogue: wave w owns rows w*4..w*4+3
  float acc_sim = 0.f;
#pragma unroll
  for (int r = 0; r < 4; ++r) {
    const int lr = w * 4 + r;
    const int row = row0 + lr;
    float suu = 0.f, suv = 0.f, svv = 0.f;
#pragma unroll
    for (int c0 = 0; c0 < FF; c0 += 64) {
      suu = fmaf(xn[(size_t)row * FF + c0 + lane], sH1[lr][c0 + lane], suu);
    }
    for (int cb = lane; cb < CC; cb += 64) {
      const float sv = sn[(size_t)row * CC + cb];
      suv = fmaf(sU[lr][cb], sv, suv);
      svv = fmaf(sH2[lr][cb], sv, svv);
    }
    suu = wave_sum(suu);
    suv = wave_sum(suv);
    svv = wave_sum(svv);
    if (lane == 0) acc_sim += suv / sqrtf(suu * svv);
  }
  if (lane == 0) redb[w] = acc_sim;
  __syncthreads();
  if (tid == 0) atomicAdd(&scalars[SC(3)], redb[0] + redb[1] + redb[2] + redb[3]);
}

// ---------------- team embedding loss + ticket finalize ----------------
__global__ __launch_bounds__(256) void k_teams(const float* __restrict__ emb,
                                               const int* __restrict__ teams,
                                               const int* __restrict__ reps,
                                               float* __restrict__ scalars,
                                               unsigned int* __restrict__ ticket,
                                               float* __restrict__ outsc) {
  __shared__ float red[4];
  const int tid = threadIdx.x;
  const int team = blockIdx.x;
  float part = 0.f;
  for (int d = tid; d < DD; d += 256) {
    float a = 0.f, b = 0.f;
#pragma unroll
    for (int m = 0; m < RR; ++m) a += emb[(size_t)reps[team * RR + m] * DD + d];
#pragma unroll
    for (int m = RR; m < TT; ++m) b += emb[(size_t)teams[team * TT + m] * DD + d];
    part += fabsf(a * (1.f / RR) - b * (1.f / (TT - RR)));
  }
  part = wave_sum(part);
  if ((tid & 63) == 0) red[tid >> 6] = part;
  __syncthreads();
  if (tid == 0) {
    atomicAdd(&scalars[SC(4)], red[0] + red[1] + red[2] + red[3]);
    __threadfence();
    const unsigned int old = atomicAdd(ticket, 1u);
    if (old == (unsigned int)(LL - 1)) {
      const float trSAS = atomicAdd(&scalars[SC(0)], 0.f);
      const float adjsq = atomicAdd(&scalars[SC(1)], 0.f);
      const float ent   = atomicAdd(&scalars[SC(2)], 0.f);
      const float simS  = atomicAdd(&scalars[SC(3)], 0.f);
      const float embS  = atomicAdd(&scalars[SC(4)], 0.f);
      const float sumP2 = atomicAdd(&scalars[SC(5)], 0.f);
      const float normsq = fmaxf(sumP2 - 2.f * trSAS + adjsq, 0.f);
      const float norm = sqrtf(normsq);
      const float e1 = ent * (1.f / NN);
      const float sim = -simS * (1.f / NN);
      const float embl = embS * (1.f / LL);
      outsc[0] = norm;
      outsc[1] = e1;
      outsc[2] = sim;
      outsc[3] = 100.f * norm + 10.f * e1 + 100.f * sim + embl;
      outsc[4] = embl;
    }
  }
}

// ================= launch =================
extern "C" void kernel_launch(void* const* d_in, const int* in_sizes, int n_in,
                              void* d_out, int out_size, void* d_ws, size_t ws_size,
                              hipStream_t stream) {
  const float* x      = (const float*)d_in[0];
  const float* adj    = (const float*)d_in[1];
  const int*   teams  = (const int*)d_in[2];
  const int*   reps   = (const int*)d_in[3];
  const float* W1r    = (const float*)d_in[4];
  const float* b1     = (const float*)d_in[5];
  const float* W1root = (const float*)d_in[6];
  const float* g1     = (const float*)d_in[7];
  const float* be1    = (const float*)d_in[8];
  const float* W2r    = (const float*)d_in[9];
  const float* b2     = (const float*)d_in[10];
  const float* W2root = (const float*)d_in[11];
  const float* g2     = (const float*)d_in[12];
  const float* be2    = (const float*)d_in[13];
  const float* W3r    = (const float*)d_in[14];
  const float* b3     = (const float*)d_in[15];
  const float* W3root = (const float*)d_in[16];
  const float* g3     = (const float*)d_in[17];
  const float* be3    = (const float*)d_in[18];
  const float* Wl1    = (const float*)d_in[19];
  const float* bl1    = (const float*)d_in[20];

  char* wp = (char*)d_ws;
  auto alloc = [&](size_t bytes) { char* p = wp; wp += (bytes + 255) & ~(size_t)255; return p; };
  unsigned short* adj_t = (unsigned short*)alloc((size_t)NN * NN * 2);
  unsigned short* mB    = (unsigned short*)alloc((size_t)HH * NN * 2);
  unsigned short* x2B   = (unsigned short*)alloc((size_t)HH * NN * 2);
  unsigned short* s1B   = (unsigned short*)alloc((size_t)GP * NN * 2);
  unsigned short* snB   = (unsigned short*)alloc((size_t)GP * NN * 2);
  unsigned short* Wl1T  = (unsigned short*)alloc((size_t)GP * DP * 2);
  unsigned short* xnR   = (unsigned short*)alloc((size_t)NN * FF * 2);
  unsigned short* snR   = (unsigned short*)alloc((size_t)NN * GTS * 2);
  float* rootb  = (float*)alloc((size_t)NN * HH * 4);
  float* t      = (float*)alloc((size_t)NN * HH * 4);
  float* x2     = (float*)alloc((size_t)NN * HH * 4);
  float* part   = (float*)alloc((size_t)KS * NN * HH * 4);
  float* t3     = (float*)alloc((size_t)NN * CC * 4);
  float* sn     = (float*)alloc((size_t)NN * CC * 4);
  float* xn     = (float*)alloc((size_t)NN * FF * 4);
  // ---- contiguous zero-init region ----
  float* scalars = (float*)alloc(256 * 4);
  float* colsum1 = (float*)alloc(512 * 4);
  float* colsq1  = (float*)alloc(512 * 4);
  float* colsum2 = (float*)alloc(512 * 4);
  float* colsq2  = (float*)alloc(512 * 4);
  float* colsum3 = (float*)alloc(4096 * 4);
  float* colsq3  = (float*)alloc(4096 * 4);
  unsigned short* GTall = (unsigned short*)alloc((size_t)3 * GP * GTS * 2);
  unsigned short* xnB   = (unsigned short*)alloc((size_t)GP * NN * 2);
  char* zero_end = wp;
  unsigned short* GT0   = GTall;
  unsigned short* GxsT  = GTall + (size_t)GP * GTS;
  unsigned short* GsT   = GTall + (size_t)2 * GP * GTS;
  unsigned int* ticket = (unsigned int*)&scalars[SC(6)];
  (void)ws_size; (void)in_sizes; (void)n_in; (void)out_size;

  float* out   = (float*)d_out;
  float* s1    = out;                          // N*C
  float* outsc = out + (size_t)NN * CC;        // 5 scalars
  float* emb   = out + (size_t)NN * CC + 5;    // N*D

  hipMemsetAsync(scalars, 0, (size_t)(zero_end - (char*)scalars), stream);

  // prep: conv1 projection + xn/xnR/xnB + Wl1T
  k_prep<<<256, 256, 0, stream>>>(x, W1r, W1root, Wl1, mB, rootb, xn, xnR, xnB, Wl1T);

  // conv1 (fused: adj cvt->tiled + adj^2 + MFMA)
  k_conv1f<<<dim3(NN / 64, KS), 256, 0, stream>>>(adj, adj_t, mB, part, scalars);
  k_epi32<<<NN * HH / 256, 256, 0, stream>>>(part, b1, rootb, t, colsum1, colsq1);
  k_bnproj<<<NN / 32, 256, 0, stream>>>(t, colsum1, colsq1, g1, be1, W2r, W2root, mB, rootb, emb);

  // conv2
  k_adjmm<<<dim3(NN / 64, KS), 256, 0, stream>>>(adj_t, mB, part);
  k_epi32<<<NN * HH / 256, 256, 0, stream>>>(part, b2, rootb, t, colsum2, colsq2);
  k_bnapply32<<<NN / 32, 256, 0, stream>>>(t, colsum2, colsq2, g2, be2, x2, emb, HH, x2B);

  // conv3
  k_adjmm<<<dim3(NN / 64, KS), 256, 0, stream>>>(adj_t, x2B, part);
  k_epi3<<<NN / 16, 256, 0, stream>>>(part, W3r, b3, x2, W3root, t3, colsum3, colsq3);

  // fused head (BN3 + emb + logits + softmax)
  k_head<<<NN / 16, 256, 0, stream>>>(emb, t3, colsum3, colsq3, g3, be3, Wl1T, bl1,
                                      s1, sn, s1B, snB, snR, scalars);

  // merged tail: norm pass + Grams
  k_tail<<<512 + 676, 512, 0, stream>>>(adj_t, s1B, s1, xnB, snB, GT0, GxsT, GsT, scalars);

  // bilinear forms + sim (H in LDS), then team loss + finalize
  k_rowsim<<<NN / 16, 256, 0, stream>>>(xnR, snR, GT0, GxsT, GsT, xn, sn, scalars);
  k_teams<<<LL, 256, 0, stream>>>(emb, teams, reps, scalars, ticket, outsc);
}

// Round 14
// 189.834 us; speedup vs baseline: 4.8728x; 1.1229x over previous
//
#include <hip/hip_runtime.h>
#include <math.h>

#define NN 4096
#define FF 128
#define HH 32
#define CC 205
#define DD 269
#define LL 512
#define TT 12
#define RR 4
#define GP 208   // padded gram dim
#define DP 288   // padded D (k) dim for logits MFMA
#define BST 40   // padded LDS row stride (ushorts) for B tiles
#define GTS 224  // transposed-gram row stride / padded K
// padded scalar slots: 0=trSAS 1=adjsq 2=entropy 3=sim 4=embloss 5=sumP2 6=ticket
#define SC(i) ((i) * 32)

typedef __attribute__((ext_vector_type(8))) short bf16x8;
typedef __attribute__((ext_vector_type(4))) float f32x4;
typedef __attribute__((ext_vector_type(8))) unsigned short u16x8;

// ---------------- helpers ----------------
__device__ __forceinline__ float wave_sum(float v) {
#pragma unroll
  for (int o = 32; o > 0; o >>= 1) v += __shfl_xor(v, o, 64);
  return v;
}
__device__ __forceinline__ float wave_max(float v) {
#pragma unroll
  for (int o = 32; o > 0; o >>= 1) v = fmaxf(v, __shfl_xor(v, o, 64));
  return v;
}
__device__ __forceinline__ unsigned short f2bf(float x) {  // RNE
  union { float f; unsigned u; } v; v.f = x;
  unsigned r = v.u + 0x7FFFu + ((v.u >> 16) & 1u);
  return (unsigned short)(r >> 16);
}

// ---------------- fused prep: [0..127] conv1 dual projection; [128..255] xn/xnR/xnB; all: Wl1T ----------------
__global__ __launch_bounds__(256) void k_prep(const float* __restrict__ x,
                                              const float* __restrict__ W1r,
                                              const float* __restrict__ W1root,
                                              const float* __restrict__ Wl1,
                                              unsigned short* __restrict__ mB,
                                              float* __restrict__ rootb,
                                              float* __restrict__ xn,
                                              unsigned short* __restrict__ xnR,
                                              unsigned short* __restrict__ xnB,
                                              unsigned short* __restrict__ Wl1T) {
  __shared__ float sX[32][132];
  __shared__ unsigned short sT[32][34];
  __shared__ unsigned short sT2[FF][34];
  const int tid = threadIdx.x;
  {
    const int i = blockIdx.x * 256 + tid;
    if (i < GP * DP) {
      const int c = i / DP, k = i - c * DP;
      Wl1T[i] = (c < CC && k < DD) ? f2bf(Wl1[(size_t)k * CC + c]) : (unsigned short)0;
    }
  }
  if (blockIdx.x < 128) {
    const int kb = blockIdx.x;
    for (int p = tid; p < 1024; p += 256) {
      const int node = p >> 5, c4 = p & 31;
      const float4 v = *reinterpret_cast<const float4*>(&x[((size_t)(kb * 32 + node)) * FF + c4 * 4]);
      sX[node][c4 * 4 + 0] = v.x; sX[node][c4 * 4 + 1] = v.y;
      sX[node][c4 * 4 + 2] = v.z; sX[node][c4 * 4 + 3] = v.w;
    }
    __syncthreads();
    const int c = tid & 31, g = tid >> 5;
    float a1[4] = {0.f, 0.f, 0.f, 0.f}, a2[4] = {0.f, 0.f, 0.f, 0.f};
    for (int k = 0; k < FF; ++k) {
      const float w1 = W1r[k * HH + c];
      const float w2 = W1root[k * HH + c];
#pragma unroll
      for (int ni = 0; ni < 4; ++ni) {
        const float av = sX[g * 4 + ni][k];
        a1[ni] = fmaf(av, w1, a1[ni]);
        a2[ni] = fmaf(av, w2, a2[ni]);
      }
    }
#pragma unroll
    for (int ni = 0; ni < 4; ++ni) {
      rootb[((size_t)kb * 32 + g * 4 + ni) * HH + c] = a2[ni];
      sT[c][g * 4 + ni] = f2bf(a1[ni]);
    }
    __syncthreads();
    if (tid < 128) {
      const int row = tid >> 2, seg = tid & 3;
      u16x8 v;
#pragma unroll
      for (int j = 0; j < 8; ++j) v[j] = sT[row][seg * 8 + j];
      *reinterpret_cast<u16x8*>(&mB[((size_t)kb * 32 + row) * 32 + seg * 8]) = v;
    }
  } else {
    const int kb = blockIdx.x - 128;
    const int lane = tid & 63;
    const int w = tid >> 6;
#pragma unroll
    for (int i = 0; i < 8; ++i) {
      const int node = w * 8 + i;
      const int row = kb * 32 + node;
      const float v0 = x[(size_t)row * FF + lane];
      const float v1 = x[(size_t)row * FF + 64 + lane];
      const float ss = wave_sum(v0 * v0 + v1 * v1);
      const float n = fmaxf(sqrtf(ss), 1e-8f);
      const float a = v0 / n, b = v1 / n;
      xn[(size_t)row * FF + lane] = a;
      xn[(size_t)row * FF + 64 + lane] = b;
      xnR[(size_t)row * FF + lane] = f2bf(a);
      xnR[(size_t)row * FF + 64 + lane] = f2bf(b);
      sT2[lane][node] = f2bf(a);
      sT2[64 + lane][node] = f2bf(b);
    }
    __syncthreads();
    const int rowc = tid >> 1, seg = (tid & 1) * 16;
    if (rowc < FF) {
      u16x8 a, b;
#pragma unroll
      for (int j = 0; j < 8; ++j) { a[j] = sT2[rowc][seg + j]; b[j] = sT2[rowc][seg + 8 + j]; }
      *reinterpret_cast<u16x8*>(&xnB[((size_t)kb * GP + rowc) * 32 + seg]) = a;
      *reinterpret_cast<u16x8*>(&xnB[((size_t)kb * GP + rowc) * 32 + seg + 8]) = b;
    }
  }
}

// ---------------- FUSED conv1 (full-K): cvt + adj_t + adj^2 + MFMA + epilogue(bias,root,relu,t,stats) ----------------
// grid 256; 512 threads; block = 16 rows; 8 chunks of 512 k-cols
__global__ __launch_bounds__(512) void k_conv1(const float* __restrict__ adj,
                                               unsigned short* __restrict__ adj_t,
                                               const unsigned short* __restrict__ mB,
                                               const float* __restrict__ bias,
                                               const float* __restrict__ root,
                                               float* __restrict__ t,
                                               float* __restrict__ colsum,
                                               float* __restrict__ colsq,
                                               float* __restrict__ scalars) {
  __shared__ unsigned short sA[16][520];
  __shared__ float sRed[8][16][33];
  __shared__ float ls[HH], lq[HH];
  __shared__ float redsq[8];
  const int tid = threadIdx.x;
  const int lane = tid & 63;
  const int w = tid >> 6;
  const int l15 = lane & 15;
  const int kgrp = (lane >> 4) * 8;
  const int rb = blockIdx.x;
  const int row0 = rb * 16;
  float adjsq = 0.f;
  f32x4 acc0 = {0.f, 0.f, 0.f, 0.f}, acc1 = {0.f, 0.f, 0.f, 0.f};
  for (int chunk = 0; chunk < 8; ++chunk) {
    const int kbase = chunk * 512;
#pragma unroll
    for (int i = 0; i < 4; ++i) {
      const int fi = i * 512 + tid;      // 0..2047 float4s of the 16x512 tile
      const int r = fi >> 7;
      const int c4 = fi & 127;
      const size_t goff = (size_t)(row0 + r) * NN + kbase + c4 * 4;
      const float4 v = *reinterpret_cast<const float4*>(&adj[goff]);
      adjsq += v.x * v.x + v.y * v.y + v.z * v.z + v.w * v.w;
      ushort4 h;
      h.x = f2bf(v.x); h.y = f2bf(v.y); h.z = f2bf(v.z); h.w = f2bf(v.w);
      const size_t toff = ((size_t)rb * (NN / 32) + (kbase >> 5) + (c4 >> 3)) * 512 +
                          r * 32 + (c4 & 7) * 4;
      *reinterpret_cast<ushort4*>(&adj_t[toff]) = h;
      *reinterpret_cast<ushort4*>(&sA[r][c4 * 4]) = h;
    }
    __syncthreads();
#pragma unroll
    for (int j = 0; j < 2; ++j) {
      const int ktl = w * 2 + j;         // 0..15 within chunk
      const bf16x8 a = *reinterpret_cast<const bf16x8*>(&sA[l15][ktl * 32 + kgrp]);
      const size_t boff = (size_t)(chunk * 16 + ktl) * 1024;
      const bf16x8 b0 = *reinterpret_cast<const bf16x8*>(&mB[boff + l15 * 32 + kgrp]);
      const bf16x8 b1v = *reinterpret_cast<const bf16x8*>(&mB[boff + (16 + l15) * 32 + kgrp]);
      acc0 = __builtin_amdgcn_mfma_f32_16x16x32_bf16(a, b0, acc0, 0, 0, 0);
      acc1 = __builtin_amdgcn_mfma_f32_16x16x32_bf16(a, b1v, acc1, 0, 0, 0);
    }
    __syncthreads();
  }
  const int crow = (lane >> 4) * 4;
#pragma unroll
  for (int r = 0; r < 4; ++r) {
    sRed[w][crow + r][l15] = acc0[r];
    sRed[w][crow + r][16 + l15] = acc1[r];
  }
  if (tid < HH) { ls[tid] = 0.f; lq[tid] = 0.f; }
  adjsq = wave_sum(adjsq);
  if (lane == 0) redsq[w] = adjsq;
  __syncthreads();
  {
    const int r = tid >> 5, c = tid & 31;
    float v = 0.f;
#pragma unroll
    for (int i = 0; i < 8; ++i) v += sRed[i][r][c];
    const int n = row0 + r;
    float s = bias[c] + root[(size_t)n * HH + c] + v;
    s = fmaxf(s, 0.f);
    t[(size_t)n * HH + c] = s;
    atomicAdd(&ls[c], s);
    atomicAdd(&lq[c], s * s);
  }
  __syncthreads();
  if (tid < HH) {
    atomicAdd(&colsum[tid * 16], ls[tid]);
    atomicAdd(&colsq[tid * 16], lq[tid]);
  }
  if (tid == 0) {
    float s = 0.f;
#pragma unroll
    for (int i = 0; i < 8; ++i) s += redsq[i];
    atomicAdd(&scalars[SC(1)], s);
  }
}

// ---------------- FUSED conv2 (full-K): adj_t @ mB + epilogue(bias,root,relu,t,stats) ----------------
// grid 256; 512 threads; block = 16 rows; wave w covers kt w*16..w*16+15
__global__ __launch_bounds__(512) void k_conv2(const unsigned short* __restrict__ adj_t,
                                               const unsigned short* __restrict__ mB,
                                               const float* __restrict__ bias,
                                               const float* __restrict__ root,
                                               float* __restrict__ t,
                                               float* __restrict__ colsum,
                                               float* __restrict__ colsq) {
  __shared__ float sRed[8][16][33];
  __shared__ float ls[HH], lq[HH];
  const int tid = threadIdx.x;
  const int lane = tid & 63;
  const int w = tid >> 6;
  const int l15 = lane & 15;
  const int kgrp = (lane >> 4) * 8;
  const int rb = blockIdx.x;
  const int row0 = rb * 16;
  const int kb0 = w * 16;
  f32x4 acc0 = {0.f, 0.f, 0.f, 0.f}, acc1 = {0.f, 0.f, 0.f, 0.f};
#pragma unroll
  for (int h = 0; h < 2; ++h) {
    bf16x8 a[8], b0[8], b1v[8];
#pragma unroll
    for (int kt = 0; kt < 8; ++kt) {
      const int kb = kb0 + h * 8 + kt;
      const size_t aoff = ((size_t)rb * (NN / 32) + kb) * 512;
      const size_t boff = (size_t)kb * 1024;
      a[kt] = *reinterpret_cast<const bf16x8*>(&adj_t[aoff + l15 * 32 + kgrp]);
      b0[kt] = *reinterpret_cast<const bf16x8*>(&mB[boff + (size_t)l15 * 32 + kgrp]);
      b1v[kt] = *reinterpret_cast<const bf16x8*>(&mB[boff + (size_t)(16 + l15) * 32 + kgrp]);
    }
#pragma unroll
    for (int kt = 0; kt < 8; ++kt) {
      acc0 = __builtin_amdgcn_mfma_f32_16x16x32_bf16(a[kt], b0[kt], acc0, 0, 0, 0);
      acc1 = __builtin_amdgcn_mfma_f32_16x16x32_bf16(a[kt], b1v[kt], acc1, 0, 0, 0);
    }
  }
  const int crow = (lane >> 4) * 4;
#pragma unroll
  for (int r = 0; r < 4; ++r) {
    sRed[w][crow + r][l15] = acc0[r];
    sRed[w][crow + r][16 + l15] = acc1[r];
  }
  if (tid < HH) { ls[tid] = 0.f; lq[tid] = 0.f; }
  __syncthreads();
  {
    const int r = tid >> 5, c = tid & 31;
    float v = 0.f;
#pragma unroll
    for (int i = 0; i < 8; ++i) v += sRed[i][r][c];
    const int n = row0 + r;
    float s = bias[c] + root[(size_t)n * HH + c] + v;
    s = fmaxf(s, 0.f);
    t[(size_t)n * HH + c] = s;
    atomicAdd(&ls[c], s);
    atomicAdd(&lq[c], s * s);
  }
  __syncthreads();
  if (tid < HH) {
    atomicAdd(&colsum[tid * 16], ls[tid]);
    atomicAdd(&colsq[tid * 16], lq[tid]);
  }
}

// ---------------- FUSED conv3 (full-K): adj_t @ x2B, then W3r/W3root GEMM epilogue + stats ----------------
// grid 256; 512 threads; block = 16 rows
__global__ __launch_bounds__(512) void k_conv3(const unsigned short* __restrict__ adj_t,
                                               const unsigned short* __restrict__ x2B,
                                               const float* __restrict__ W3r,
                                               const float* __restrict__ b3,
                                               const float* __restrict__ x2,
                                               const float* __restrict__ W3root,
                                               float* __restrict__ t3,
                                               float* __restrict__ colsum,
                                               float* __restrict__ colsq) {
  __shared__ float sRed[8][16][33];
  __shared__ float sZ[16][33];
  __shared__ float sXr[16][33];
  const int tid = threadIdx.x;
  const int lane = tid & 63;
  const int w = tid >> 6;
  const int l15 = lane & 15;
  const int kgrp = (lane >> 4) * 8;
  const int rb = blockIdx.x;
  const int row0 = rb * 16;
  const int kb0 = w * 16;
  f32x4 acc0 = {0.f, 0.f, 0.f, 0.f}, acc1 = {0.f, 0.f, 0.f, 0.f};
#pragma unroll
  for (int h = 0; h < 2; ++h) {
    bf16x8 a[8], b0[8], b1v[8];
#pragma unroll
    for (int kt = 0; kt < 8; ++kt) {
      const int kb = kb0 + h * 8 + kt;
      const size_t aoff = ((size_t)rb * (NN / 32) + kb) * 512;
      const size_t boff = (size_t)kb * 1024;
      a[kt] = *reinterpret_cast<const bf16x8*>(&adj_t[aoff + l15 * 32 + kgrp]);
      b0[kt] = *reinterpret_cast<const bf16x8*>(&x2B[boff + (size_t)l15 * 32 + kgrp]);
      b1v[kt] = *reinterpret_cast<const bf16x8*>(&x2B[boff + (size_t)(16 + l15) * 32 + kgrp]);
    }
#pragma unroll
    for (int kt = 0; kt < 8; ++kt) {
      acc0 = __builtin_amdgcn_mfma_f32_16x16x32_bf16(a[kt], b0[kt], acc0, 0, 0, 0);
      acc1 = __builtin_amdgcn_mfma_f32_16x16x32_bf16(a[kt], b1v[kt], acc1, 0, 0, 0);
    }
  }
  const int crow = (lane >> 4) * 4;
#pragma unroll
  for (int r = 0; r < 4; ++r) {
    sRed[w][crow + r][l15] = acc0[r];
    sRed[w][crow + r][16 + l15] = acc1[r];
  }
  // stage x2 rows
  {
    const int r = tid >> 5, c = tid & 31;
    sXr[r][c] = x2[(size_t)(row0 + r) * HH + c];
  }
  __syncthreads();
  {
    const int r = tid >> 5, c = tid & 31;
    float v = 0.f;
#pragma unroll
    for (int i = 0; i < 8; ++i) v += sRed[i][r][c];
    sZ[r][c] = v;
  }
  __syncthreads();
  const int c = tid;
  if (c >= CC) return;
  float acc[16];
  const float bb = b3[c];
#pragma unroll
  for (int r = 0; r < 16; ++r) acc[r] = bb;
  for (int k = 0; k < 32; ++k) {
    const float w1 = W3r[k * CC + c];
    const float w2 = W3root[k * CC + c];
#pragma unroll
    for (int r = 0; r < 16; ++r) acc[r] += sZ[r][k] * w1 + sXr[r][k] * w2;
  }
  float lsm = 0.f, lqm = 0.f;
#pragma unroll
  for (int r = 0; r < 16; ++r) {
    const float v = fmaxf(acc[r], 0.f);
    t3[(size_t)(row0 + r) * CC + c] = v;
    lsm += v;
    lqm += v * v;
  }
  atomicAdd(&colsum[c * 16], lsm);
  atomicAdd(&colsq[c * 16], lqm);
}

// ---------------- FUSED: BN1 apply (inline stats) + emb write + conv2 dual projection ----------------
__global__ __launch_bounds__(256) void k_bnproj(const float* __restrict__ t,
                                                const float* __restrict__ colsum,
                                                const float* __restrict__ colsq,
                                                const float* __restrict__ g,
                                                const float* __restrict__ be,
                                                const float* __restrict__ W2r,
                                                const float* __restrict__ W2root,
                                                unsigned short* __restrict__ mB,
                                                float* __restrict__ rootb,
                                                float* __restrict__ emb) {
  __shared__ float sXf[32][33];
  __shared__ unsigned short sT[32][34];
  const int tid = threadIdx.x;
  const int kb = blockIdx.x;
  const int c = tid & 31, gq = tid >> 5;
  const float m = colsum[c * 16] * (1.f / NN);
  const float var = fmaxf(colsq[c * 16] * (1.f / NN) - m * m, 0.f);
  const float Ac = g[c] / sqrtf(var + 1e-5f);
  const float Bc = be[c] - m * Ac;
#pragma unroll
  for (int ni = 0; ni < 4; ++ni) {
    const int n = kb * 32 + gq * 4 + ni;
    const float v = fmaf(Ac, t[(size_t)n * HH + c], Bc);
    emb[(size_t)n * DD + c] = v;
    sXf[gq * 4 + ni][c] = v;
  }
  __syncthreads();
  float a1[4] = {0.f, 0.f, 0.f, 0.f}, a2[4] = {0.f, 0.f, 0.f, 0.f};
  for (int k = 0; k < HH; ++k) {
    const float w1 = W2r[k * HH + c];
    const float w2 = W2root[k * HH + c];
#pragma unroll
    for (int ni = 0; ni < 4; ++ni) {
      const float av = sXf[gq * 4 + ni][k];
      a1[ni] = fmaf(av, w1, a1[ni]);
      a2[ni] = fmaf(av, w2, a2[ni]);
    }
  }
#pragma unroll
  for (int ni = 0; ni < 4; ++ni) {
    rootb[((size_t)kb * 32 + gq * 4 + ni) * HH + c] = a2[ni];
    sT[c][gq * 4 + ni] = f2bf(a1[ni]);
  }
  __syncthreads();
  if (tid < 128) {
    const int row = tid >> 2, seg = tid & 3;
    u16x8 v;
#pragma unroll
    for (int j = 0; j < 8; ++j) v[j] = sT[row][seg * 8 + j];
    *reinterpret_cast<u16x8*>(&mB[((size_t)kb * 32 + row) * 32 + seg * 8]) = v;
  }
}

// ---------------- bn apply conv2 (inline stats) + x2 + emb + tiled x2B ----------------
__global__ __launch_bounds__(256) void k_bnapply32(const float* __restrict__ t,
                                                   const float* __restrict__ colsum,
                                                   const float* __restrict__ colsq,
                                                   const float* __restrict__ g,
                                                   const float* __restrict__ be,
                                                   float* __restrict__ xo,
                                                   float* __restrict__ emb, int embOff,
                                                   unsigned short* __restrict__ xB) {
  __shared__ unsigned short sT[32][34];
  const int tid = threadIdx.x;
  const int kb = blockIdx.x;
  const int c = tid & 31, gq = tid >> 5;
  const float m = colsum[c * 16] * (1.f / NN);
  const float var = fmaxf(colsq[c * 16] * (1.f / NN) - m * m, 0.f);
  const float Ac = g[c] / sqrtf(var + 1e-5f);
  const float Bc = be[c] - m * Ac;
#pragma unroll
  for (int ni = 0; ni < 4; ++ni) {
    const int n = kb * 32 + gq * 4 + ni;
    const float v = fmaf(Ac, t[(size_t)n * HH + c], Bc);
    xo[(size_t)n * HH + c] = v;
    emb[(size_t)n * DD + embOff + c] = v;
    sT[c][gq * 4 + ni] = f2bf(v);
  }
  __syncthreads();
  if (tid < 128) {
    const int row = tid >> 2, seg = tid & 3;
    u16x8 o;
#pragma unroll
    for (int j = 0; j < 8; ++j) o[j] = sT[row][seg * 8 + j];
    *reinterpret_cast<u16x8*>(&xB[((size_t)kb * 32 + row) * 32 + seg * 8]) = o;
  }
}

// ---------------- fused head: BN3 inline + emb write + MFMA logits + softmax ----------------
__global__ __launch_bounds__(256) void k_head(float* __restrict__ emb,
                                              const float* __restrict__ t3,
                                              const float* __restrict__ colsum3,
                                              const float* __restrict__ colsq3,
                                              const float* __restrict__ g3,
                                              const float* __restrict__ be3,
                                              const unsigned short* __restrict__ Wl1T,
                                              const float* __restrict__ bl1,
                                              float* __restrict__ s1,
                                              float* __restrict__ sn,
                                              unsigned short* __restrict__ s1B,
                                              unsigned short* __restrict__ snB,
                                              unsigned short* __restrict__ snR,
                                              float* __restrict__ scalars) {
  __shared__ unsigned short sA[16][296];
  __shared__ float lg[16][212];
  __shared__ unsigned short sTa[16][212];
  __shared__ unsigned short sTb[16][212];
  __shared__ float redE[4];
  const int tid = threadIdx.x;
  const int row0 = blockIdx.x * 16;
  for (int p = tid; p < 16 * 36; p += 256) {
    const int r = p / 36, ch = p - r * 36;
    const int row = row0 + r;
#pragma unroll
    for (int j = 0; j < 8; ++j) {
      const int d = ch * 8 + j;
      float v;
      if (d < 2 * HH) {
        v = emb[(size_t)row * DD + d];
      } else if (d < DD) {
        const int c3 = d - 2 * HH;
        const float m = colsum3[c3 * 16] * (1.f / NN);
        const float var = fmaxf(colsq3[c3 * 16] * (1.f / NN) - m * m, 0.f);
        const float Ac = g3[c3] / sqrtf(var + 1e-5f);
        const float Bc = be3[c3] - m * Ac;
        v = fmaf(Ac, t3[(size_t)row * CC + c3], Bc);
        emb[(size_t)row * DD + d] = v;
      } else {
        v = 0.f;
      }
      sA[r][d] = f2bf(v);
    }
  }
  __syncthreads();
  const int lane = tid & 63;
  const int w = tid >> 6;
  const int l15 = lane & 15;
  const int kgrp = (lane >> 4) * 8;
  {
    f32x4 acc[4];
#pragma unroll
    for (int i = 0; i < 4; ++i) acc[i] = (f32x4){0.f, 0.f, 0.f, 0.f};
#pragma unroll
    for (int i = 0; i < 4; ++i) {
      const int ct = w + i * 4;
      if (ct < 13) {
        const size_t brow = (size_t)(ct * 16 + l15) * DP;
#pragma unroll
        for (int k0 = 0; k0 < DP; k0 += 32) {
          const bf16x8 a = *reinterpret_cast<const bf16x8*>(&sA[l15][k0 + kgrp]);
          const bf16x8 b = *reinterpret_cast<const bf16x8*>(&Wl1T[brow + k0 + kgrp]);
          acc[i] = __builtin_amdgcn_mfma_f32_16x16x32_bf16(a, b, acc[i], 0, 0, 0);
        }
      }
    }
    const int lrow = (lane >> 4) * 4;
#pragma unroll
    for (int i = 0; i < 4; ++i) {
      const int ct = w + i * 4;
      if (ct < 13) {
#pragma unroll
        for (int r = 0; r < 4; ++r) lg[lrow + r][ct * 16 + l15] = acc[i][r];
      }
    }
  }
  __syncthreads();
  const int r0 = w * 4;
  const int c0 = lane * 4;
  const bool active = (c0 < GP);
  float bl[4];
#pragma unroll
  for (int j = 0; j < 4; ++j) bl[j] = (c0 + j < CC) ? bl1[c0 + j] : 0.f;
  float ent_acc = 0.f;
#pragma unroll
  for (int r = 0; r < 4; ++r) {
    const int lr = r0 + r;
    const int row = row0 + lr;
    float lgv[4] = {0.f, 0.f, 0.f, 0.f};
    if (active) {
#pragma unroll
      for (int j = 0; j < 4; ++j) lgv[j] = lg[lr][c0 + j];
    }
    float v[4];
    float ml = -1e30f;
#pragma unroll
    for (int j = 0; j < 4; ++j) {
      const int c = c0 + j;
      v[j] = (c < CC) ? fmaxf(lgv[j] + bl[j], 0.f) : -1e30f;
      ml = fmaxf(ml, v[j]);
    }
    const float m = wave_max(ml);
    float e[4];
    float sl = 0.f;
#pragma unroll
    for (int j = 0; j < 4; ++j) {
      const int c = c0 + j;
      e[j] = (c < CC) ? __expf(v[j] - m) : 0.f;
      sl += e[j];
    }
    const float S = wave_sum(sl);
    const float invS = 1.f / S;
    float p[4];
    float ql = 0.f;
#pragma unroll
    for (int j = 0; j < 4; ++j) {
      p[j] = e[j] * invS;
      ql += p[j] * p[j];
    }
    const float q = wave_sum(ql);
    const float inv = 1.f / fmaxf(sqrtf(q), 1e-8f);
    float m2l = -1e30f;
#pragma unroll
    for (int j = 0; j < 4; ++j) {
      const int c = c0 + j;
      if (c < CC) {
        s1[(size_t)row * CC + c] = p[j];
        sn[(size_t)row * CC + c] = p[j] * inv;
        m2l = fmaxf(m2l, p[j]);
      }
    }
    if (active) {
#pragma unroll
      for (int j = 0; j < 4; ++j) {
        const int c = c0 + j;
        const bool ok = (c < CC);
        sTa[lr][c] = ok ? f2bf(p[j]) : (unsigned short)0;
        sTb[lr][c] = ok ? f2bf(p[j] * inv) : (unsigned short)0;
      }
    }
    if (c0 < GTS) {
      ushort4 o;
      o.x = (c0 + 0 < CC) ? f2bf(p[0] * inv) : (unsigned short)0;
      o.y = (c0 + 1 < CC) ? f2bf(p[1] * inv) : (unsigned short)0;
      o.z = (c0 + 2 < CC) ? f2bf(p[2] * inv) : (unsigned short)0;
      o.w = (c0 + 3 < CC) ? f2bf(p[3] * inv) : (unsigned short)0;
      *reinterpret_cast<ushort4*>(&snR[(size_t)row * GTS + c0]) = o;
    }
    const float m2 = wave_max(m2l);
    float e2[4];
    float s2l = 0.f;
#pragma unroll
    for (int j = 0; j < 4; ++j) {
      const int c = c0 + j;
      e2[j] = (c < CC) ? __expf(p[j] - m2) : 0.f;
      s2l += e2[j];
    }
    const float S2 = wave_sum(s2l);
    const float invS2 = 1.f / S2;
    float tl = 0.f;
#pragma unroll
    for (int j = 0; j < 4; ++j) {
      const int c = c0 + j;
      if (c < CC) {
        const float sp = e2[j] * invS2;
        tl -= sp * logf(sp + 1e-15f);
      }
    }
    ent_acc += tl;
  }
  ent_acc = wave_sum(ent_acc);
  if (lane == 0) redE[w] = ent_acc;
  __syncthreads();
  if (tid == 0) atomicAdd(&scalars[SC(2)], redE[0] + redE[1] + redE[2] + redE[3]);
  if (tid < GP) {
    const int kb = row0 >> 5, no = row0 & 31;
    u16x8 oa0, ob0, oa1, ob1;
#pragma unroll
    for (int r = 0; r < 8; ++r) {
      oa0[r] = sTa[r][tid]; ob0[r] = sTb[r][tid];
      oa1[r] = sTa[8 + r][tid]; ob1[r] = sTb[8 + r][tid];
    }
    *reinterpret_cast<u16x8*>(&s1B[((size_t)kb * GP + tid) * 32 + no]) = oa0;
    *reinterpret_cast<u16x8*>(&s1B[((size_t)kb * GP + tid) * 32 + no + 8]) = oa1;
    *reinterpret_cast<u16x8*>(&snB[((size_t)kb * GP + tid) * 32 + no]) = ob0;
    *reinterpret_cast<u16x8*>(&snB[((size_t)kb * GP + tid) * 32 + no + 8]) = ob1;
  }
}

// ---------------- merged tail: [0..511] norm pass; [512..1187] Grams (8-wave k-split) ----------------
__global__ __launch_bounds__(512) void k_tail(const unsigned short* __restrict__ adj_t,
                                              const unsigned short* __restrict__ s1B,
                                              const float* __restrict__ s1,
                                              const unsigned short* __restrict__ xnB,
                                              const unsigned short* __restrict__ snB,
                                              unsigned short* __restrict__ GT0,
                                              unsigned short* __restrict__ GxsT,
                                              unsigned short* __restrict__ GsT,
                                              float* __restrict__ scalars) {
  const int tid = threadIdx.x;
  const int lane = tid & 63;
  const int w = tid >> 6;
  const int l15 = lane & 15;
  const int kgrp = (lane >> 4) * 8;
  if (blockIdx.x < 512) {
    __shared__ unsigned short sB[2][13][16][BST];
    __shared__ float red[8];
    const int bx = blockIdx.x & 31;
    const int ky = blockIdx.x >> 5;
    const int rb = bx * 8 + w;
    const int kb0 = ky * 8;
    const int g = lane >> 4;
    const int p0 = tid;
    const int ct0 = p0 >> 6, rr0 = (p0 >> 2) & 15, sg0 = (p0 & 3) * 8;
    const int p1 = tid + 512;
    const bool v1 = (p1 < 832);
    const int ct1 = p1 >> 6, rr1 = (p1 >> 2) & 15, sg1 = (p1 & 3) * 8;
    f32x4 acc[13];
#pragma unroll
    for (int ct = 0; ct < 13; ++ct) acc[ct] = (f32x4){0.f, 0.f, 0.f, 0.f};
    u16x8 st0, st1;
    st0 = *reinterpret_cast<const u16x8*>(&s1B[((size_t)kb0 * GP + ct0 * 16 + rr0) * 32 + sg0]);
    if (v1) st1 = *reinterpret_cast<const u16x8*>(&s1B[((size_t)kb0 * GP + ct1 * 16 + rr1) * 32 + sg1]);
    *reinterpret_cast<u16x8*>(&sB[0][ct0][rr0][sg0]) = st0;
    if (v1) *reinterpret_cast<u16x8*>(&sB[0][ct1][rr1][sg1]) = st1;
    __syncthreads();
    bf16x8 a = *reinterpret_cast<const bf16x8*>(
        &adj_t[((size_t)rb * (NN / 32) + kb0) * 512 + l15 * 32 + kgrp]);
    for (int kt = 0; kt < 8; ++kt) {
      const int cur = kt & 1;
      if (kt < 7) {
        const size_t kb = kb0 + kt + 1;
        st0 = *reinterpret_cast<const u16x8*>(&s1B[(kb * GP + ct0 * 16 + rr0) * 32 + sg0]);
        if (v1) st1 = *reinterpret_cast<const u16x8*>(&s1B[(kb * GP + ct1 * 16 + rr1) * 32 + sg1]);
      }
      bf16x8 a_next = a;
      if (kt < 7)
        a_next = *reinterpret_cast<const bf16x8*>(
            &adj_t[((size_t)rb * (NN / 32) + kb0 + kt + 1) * 512 + l15 * 32 + kgrp]);
#pragma unroll
      for (int ct = 0; ct < 13; ++ct) {
        const bf16x8 b = *reinterpret_cast<const bf16x8*>(&sB[cur][ct][l15][kgrp]);
        acc[ct] = __builtin_amdgcn_mfma_f32_16x16x32_bf16(a, b, acc[ct], 0, 0, 0);
      }
      if (kt < 7) {
        *reinterpret_cast<u16x8*>(&sB[cur ^ 1][ct0][rr0][sg0]) = st0;
        if (v1) *reinterpret_cast<u16x8*>(&sB[cur ^ 1][ct1][rr1][sg1]) = st1;
      }
      __syncthreads();
      a = a_next;
    }
    const int rout = rb * 16 + g * 4;
    float sc = 0.f;
#pragma unroll
    for (int ct = 0; ct < 13; ++ct) {
      const int col = ct * 16 + l15;
      if (col < CC) {
#pragma unroll
        for (int r = 0; r < 4; ++r)
          sc = fmaf(acc[ct][r], s1[(size_t)(rout + r) * CC + col], sc);
      }
    }
    sc = wave_sum(sc);
    if (lane == 0) red[w] = sc;
    __syncthreads();
    if (tid == 0) {
      float s = 0.f;
#pragma unroll
      for (int i = 0; i < 8; ++i) s += red[i];
      atomicAdd(&scalars[SC(0)], s);
    }
  } else {
    __shared__ float redg[8][16][17];
    __shared__ float redq[8];
    const int gb = blockIdx.x - 512;
    const int gid = gb / 169;
    const int rem = gb - gid * 169;
    const int tp = (rem % 13) * 16;
    const int tq = (rem / 13) * 16;
    const unsigned short *PT, *QT;
    unsigned short* GTout = nullptr;
    if (gid == 0)      { PT = xnB; QT = xnB; GTout = GT0;  if (tp >= FF || tq >= FF) return; }
    else if (gid == 1) { PT = xnB; QT = snB; GTout = GxsT; if (tp >= FF) return; }
    else if (gid == 2) { PT = snB; QT = snB; GTout = GsT; }
    else               { PT = s1B; QT = s1B; }
    f32x4 acc = {0.f, 0.f, 0.f, 0.f};
#pragma unroll 4
    for (int kt = 0; kt < 16; ++kt) {
      const int kb = w * 16 + kt;
      const bf16x8 a = *reinterpret_cast<const bf16x8*>(&PT[((size_t)kb * GP + tp + l15) * 32 + kgrp]);
      const bf16x8 b = *reinterpret_cast<const bf16x8*>(&QT[((size_t)kb * GP + tq + l15) * 32 + kgrp]);
      acc = __builtin_amdgcn_mfma_f32_16x16x32_bf16(a, b, acc, 0, 0, 0);
    }
    const int crow = (lane >> 4) * 4;
#pragma unroll
    for (int r = 0; r < 4; ++r) redg[w][crow + r][l15] = acc[r];
    __syncthreads();
    const int rr = tid >> 4, cc = tid & 15;
    if (gid == 3) {
      float q = 0.f;
      if (tid < 256) {
        float v = 0.f;
#pragma unroll
        for (int i = 0; i < 8; ++i) v += redg[i][rr][cc];
        q = v * v;
      }
      q = wave_sum(q);
      if (lane == 0) redq[w] = q;
      __syncthreads();
      if (tid == 0) {
        float s = 0.f;
#pragma unroll
        for (int i = 0; i < 8; ++i) s += redq[i];
        atomicAdd(&scalars[SC(5)], s);
      }
    } else {
      if (tid < 256) {
        float vt = 0.f;
#pragma unroll
        for (int i = 0; i < 8; ++i) vt += redg[i][cc][rr];
        GTout[(size_t)(tq + rr) * GTS + (tp + cc)] = f2bf(vt);
      }
    }
  }
}

// ---------------- fused bilinear forms + sim: H kept in LDS, sim contracted in-kernel ----------------
__global__ __launch_bounds__(256) void k_rowsim(const unsigned short* __restrict__ xnR,
                                                const unsigned short* __restrict__ snR,
                                                const unsigned short* __restrict__ GT0,
                                                const unsigned short* __restrict__ GxsT,
                                                const unsigned short* __restrict__ GsT,
                                                const float* __restrict__ xn,
                                                const float* __restrict__ sn,
                                                float* __restrict__ scalars) {
  __shared__ unsigned short sX[16][136];
  __shared__ unsigned short sS[16][232];
  __shared__ float sH1[16][132];
  __shared__ float sU[16][212];
  __shared__ float sH2[16][212];
  __shared__ float redb[4];
  const int tid = threadIdx.x;
  const int row0 = blockIdx.x * 16;
  for (int p = tid; p < 16 * 16; p += 256) {
    const int r = p >> 4, ch = p & 15;
    *reinterpret_cast<u16x8*>(&sX[r][ch * 8]) =
        *reinterpret_cast<const u16x8*>(&xnR[(size_t)(row0 + r) * FF + ch * 8]);
  }
  for (int p = tid; p < 16 * 28; p += 256) {
    const int r = p / 28, ch = p - r * 28;
    *reinterpret_cast<u16x8*>(&sS[r][ch * 8]) =
        *reinterpret_cast<const u16x8*>(&snR[(size_t)(row0 + r) * GTS + ch * 8]);
  }
  __syncthreads();
  const int lane = tid & 63;
  const int w = tid >> 6;
  const int l15 = lane & 15;
  const int kgrp = (lane >> 4) * 8;
  const int lrow = (lane >> 4) * 4;
#pragma unroll
  for (int i = 0; i < 2; ++i) {
    const int ct = w + i * 4;
    f32x4 acc = {0.f, 0.f, 0.f, 0.f};
    const size_t brow = (size_t)(ct * 16 + l15) * GTS;
#pragma unroll
    for (int k0 = 0; k0 < FF; k0 += 32) {
      const bf16x8 a = *reinterpret_cast<const bf16x8*>(&sX[l15][k0 + kgrp]);
      const bf16x8 b = *reinterpret_cast<const bf16x8*>(&GT0[brow + k0 + kgrp]);
      acc = __builtin_amdgcn_mfma_f32_16x16x32_bf16(a, b, acc, 0, 0, 0);
    }
#pragma unroll
    for (int r = 0; r < 4; ++r) sH1[lrow + r][ct * 16 + l15] = acc[r];
  }
#pragma unroll
  for (int i = 0; i < 4; ++i) {
    const int ct = w + i * 4;
    if (ct < 13) {
      f32x4 acc = {0.f, 0.f, 0.f, 0.f};
      const size_t brow = (size_t)(ct * 16 + l15) * GTS;
#pragma unroll
      for (int k0 = 0; k0 < FF; k0 += 32) {
        const bf16x8 a = *reinterpret_cast<const bf16x8*>(&sX[l15][k0 + kgrp]);
        const bf16x8 b = *reinterpret_cast<const bf16x8*>(&GxsT[brow + k0 + kgrp]);
        acc = __builtin_amdgcn_mfma_f32_16x16x32_bf16(a, b, acc, 0, 0, 0);
      }
#pragma unroll
      for (int r = 0; r < 4; ++r) sU[lrow + r][ct * 16 + l15] = acc[r];
    }
  }
#pragma unroll
  for (int i = 0; i < 4; ++i) {
    const int ct = w + i * 4;
    if (ct < 13) {
      f32x4 acc = {0.f, 0.f, 0.f, 0.f};
      const size_t brow = (size_t)(ct * 16 + l15) * GTS;
#pragma unroll
      for (int k0 = 0; k0 < GTS; k0 += 32) {
        const bf16x8 a = *reinterpret_cast<const bf16x8*>(&sS[l15][k0 + kgrp]);
        const bf16x8 b = *reinterpret_cast<const bf16x8*>(&GsT[brow + k0 + kgrp]);
        acc = __builtin_amdgcn_mfma_f32_16x16x32_bf16(a, b, acc, 0, 0, 0);
      }
#pragma unroll
      for (int r = 0; r < 4; ++r) sH2[lrow + r][ct * 16 + l15] = acc[r];
    }
  }
  __syncthreads();
  float acc_sim = 0.f;
#pragma unroll
  for (int r = 0; r < 4; ++r) {
    const int lr = w * 4 + r;
    const int row = row0 + lr;
    float suu = 0.f, suv = 0.f, svv = 0.f;
#pragma unroll
    for (int c0 = 0; c0 < FF; c0 += 64) {
      suu = fmaf(xn[(size_t)row * FF + c0 + lane], sH1[lr][c0 + lane], suu);
    }
    for (int cb = lane; cb < CC; cb += 64) {
      const float sv = sn[(size_t)row * CC + cb];
      suv = fmaf(sU[lr][cb], sv, suv);
      svv = fmaf(sH2[lr][cb], sv, svv);
    }
    suu = wave_sum(suu);
    suv = wave_sum(suv);
    svv = wave_sum(svv);
    if (lane == 0) acc_sim += suv / sqrtf(suu * svv);
  }
  if (lane == 0) redb[w] = acc_sim;
  __syncthreads();
  if (tid == 0) atomicAdd(&scalars[SC(3)], redb[0] + redb[1] + redb[2] + redb[3]);
}

// ---------------- team embedding loss + ticket finalize ----------------
__global__ __launch_bounds__(256) void k_teams(const float* __restrict__ emb,
                                               const int* __restrict__ teams,
                                               const int* __restrict__ reps,
                                               float* __restrict__ scalars,
                                               unsigned int* __restrict__ ticket,
                                               float* __restrict__ outsc) {
  __shared__ float red[4];
  const int tid = threadIdx.x;
  const int team = blockIdx.x;
  float part = 0.f;
  for (int d = tid; d < DD; d += 256) {
    float a = 0.f, b = 0.f;
#pragma unroll
    for (int m = 0; m < RR; ++m) a += emb[(size_t)reps[team * RR + m] * DD + d];
#pragma unroll
    for (int m = RR; m < TT; ++m) b += emb[(size_t)teams[team * TT + m] * DD + d];
    part += fabsf(a * (1.f / RR) - b * (1.f / (TT - RR)));
  }
  part = wave_sum(part);
  if ((tid & 63) == 0) red[tid >> 6] = part;
  __syncthreads();
  if (tid == 0) {
    atomicAdd(&scalars[SC(4)], red[0] + red[1] + red[2] + red[3]);
    __threadfence();
    const unsigned int old = atomicAdd(ticket, 1u);
    if (old == (unsigned int)(LL - 1)) {
      const float trSAS = atomicAdd(&scalars[SC(0)], 0.f);
      const float adjsq = atomicAdd(&scalars[SC(1)], 0.f);
      const float ent   = atomicAdd(&scalars[SC(2)], 0.f);
      const float simS  = atomicAdd(&scalars[SC(3)], 0.f);
      const float embS  = atomicAdd(&scalars[SC(4)], 0.f);
      const float sumP2 = atomicAdd(&scalars[SC(5)], 0.f);
      const float normsq = fmaxf(sumP2 - 2.f * trSAS + adjsq, 0.f);
      const float norm = sqrtf(normsq);
      const float e1 = ent * (1.f / NN);
      const float sim = -simS * (1.f / NN);
      const float embl = embS * (1.f / LL);
      outsc[0] = norm;
      outsc[1] = e1;
      outsc[2] = sim;
      outsc[3] = 100.f * norm + 10.f * e1 + 100.f * sim + embl;
      outsc[4] = embl;
    }
  }
}

// ================= launch =================
extern "C" void kernel_launch(void* const* d_in, const int* in_sizes, int n_in,
                              void* d_out, int out_size, void* d_ws, size_t ws_size,
                              hipStream_t stream) {
  const float* x      = (const float*)d_in[0];
  const float* adj    = (const float*)d_in[1];
  const int*   teams  = (const int*)d_in[2];
  const int*   reps   = (const int*)d_in[3];
  const float* W1r    = (const float*)d_in[4];
  const float* b1     = (const float*)d_in[5];
  const float* W1root = (const float*)d_in[6];
  const float* g1     = (const float*)d_in[7];
  const float* be1    = (const float*)d_in[8];
  const float* W2r    = (const float*)d_in[9];
  const float* b2     = (const float*)d_in[10];
  const float* W2root = (const float*)d_in[11];
  const float* g2     = (const float*)d_in[12];
  const float* be2    = (const float*)d_in[13];
  const float* W3r    = (const float*)d_in[14];
  const float* b3     = (const float*)d_in[15];
  const float* W3root = (const float*)d_in[16];
  const float* g3     = (const float*)d_in[17];
  const float* be3    = (const float*)d_in[18];
  const float* Wl1    = (const float*)d_in[19];
  const float* bl1    = (const float*)d_in[20];

  char* wp = (char*)d_ws;
  auto alloc = [&](size_t bytes) { char* p = wp; wp += (bytes + 255) & ~(size_t)255; return p; };
  unsigned short* adj_t = (unsigned short*)alloc((size_t)NN * NN * 2);
  unsigned short* mB    = (unsigned short*)alloc((size_t)HH * NN * 2);
  unsigned short* x2B   = (unsigned short*)alloc((size_t)HH * NN * 2);
  unsigned short* s1B   = (unsigned short*)alloc((size_t)GP * NN * 2);
  unsigned short* snB   = (unsigned short*)alloc((size_t)GP * NN * 2);
  unsigned short* Wl1T  = (unsigned short*)alloc((size_t)GP * DP * 2);
  unsigned short* xnR   = (unsigned short*)alloc((size_t)NN * FF * 2);
  unsigned short* snR   = (unsigned short*)alloc((size_t)NN * GTS * 2);
  float* rootb  = (float*)alloc((size_t)NN * HH * 4);
  float* t      = (float*)alloc((size_t)NN * HH * 4);
  float* x2     = (float*)alloc((size_t)NN * HH * 4);
  float* t3     = (float*)alloc((size_t)NN * CC * 4);
  float* sn     = (float*)alloc((size_t)NN * CC * 4);
  float* xn     = (float*)alloc((size_t)NN * FF * 4);
  // ---- contiguous zero-init region ----
  float* scalars = (float*)alloc(256 * 4);
  float* colsum1 = (float*)alloc(512 * 4);
  float* colsq1  = (float*)alloc(512 * 4);
  float* colsum2 = (float*)alloc(512 * 4);
  float* colsq2  = (float*)alloc(512 * 4);
  float* colsum3 = (float*)alloc(4096 * 4);
  float* colsq3  = (float*)alloc(4096 * 4);
  unsigned short* GTall = (unsigned short*)alloc((size_t)3 * GP * GTS * 2);
  unsigned short* xnB   = (unsigned short*)alloc((size_t)GP * NN * 2);
  char* zero_end = wp;
  unsigned short* GT0   = GTall;
  unsigned short* GxsT  = GTall + (size_t)GP * GTS;
  unsigned short* GsT   = GTall + (size_t)2 * GP * GTS;
  unsigned int* ticket = (unsigned int*)&scalars[SC(6)];
  (void)ws_size; (void)in_sizes; (void)n_in; (void)out_size;

  float* out   = (float*)d_out;
  float* s1    = out;                          // N*C
  float* outsc = out + (size_t)NN * CC;        // 5 scalars
  float* emb   = out + (size_t)NN * CC + 5;    // N*D

  hipMemsetAsync(scalars, 0, (size_t)(zero_end - (char*)scalars), stream);

  // prep: conv1 projection + xn/xnR/xnB + Wl1T
  k_prep<<<256, 256, 0, stream>>>(x, W1r, W1root, Wl1, mB, rootb, xn, xnR, xnB, Wl1T);

  // conv1 (full-K fused: cvt + adj^2 + MFMA + stats)
  k_conv1<<<256, 512, 0, stream>>>(adj, adj_t, mB, b1, rootb, t, colsum1, colsq1, scalars);
  k_bnproj<<<NN / 32, 256, 0, stream>>>(t, colsum1, colsq1, g1, be1, W2r, W2root, mB, rootb, emb);

  // conv2 (full-K fused)
  k_conv2<<<256, 512, 0, stream>>>(adj_t, mB, b2, rootb, t, colsum2, colsq2);
  k_bnapply32<<<NN / 32, 256, 0, stream>>>(t, colsum2, colsq2, g2, be2, x2, emb, HH, x2B);

  // conv3 (full-K fused + W3 GEMM epilogue)
  k_conv3<<<256, 512, 0, stream>>>(adj_t, x2B, W3r, b3, x2, W3root, t3, colsum3, colsq3);

  // fused head (BN3 + emb + logits + softmax)
  k_head<<<NN / 16, 256, 0, stream>>>(emb, t3, colsum3, colsq3, g3, be3, Wl1T, bl1,
                                      s1, sn, s1B, snB, snR, scalars);

  // merged tail: norm pass + Grams
  k_tail<<<512 + 676, 512, 0, stream>>>(adj_t, s1B, s1, xnB, snB, GT0, GxsT, GsT, scalars);

  // bilinear forms + sim (H in LDS), then team loss + finalize
  k_rowsim<<<NN / 16, 256, 0, stream>>>(xnR, snR, GT0, GxsT, GsT, xn, sn, scalars);
  k_teams<<<LL, 256, 0, stream>>>(emb, teams, reps, scalars, ticket, outsc);
}

// Round 15
// 181.792 us; speedup vs baseline: 5.0884x; 1.0442x over previous
//
#include <hip/hip_runtime.h>
#include <math.h>

#define NN 4096
#define FF 128
#define HH 32
#define CC 205
#define DD 269
#define LL 512
#define TT 12
#define RR 4
#define GP 208   // padded gram dim
#define DP 288   // padded D (k) dim for logits MFMA
#define BST 40   // padded LDS row stride (ushorts) for B tiles
#define GTS 224  // transposed-gram row stride / padded K
#define NFIN 768 // blocks in k_finloss (256 rowsim + 512 teams)
// padded scalar slots: 0=trSAS 1=adjsq 2=entropy 3=sim 4=embloss 5=sumP2 6=ticket
#define SC(i) ((i) * 32)
#define ZSTATS_N 10496  // floats: scalars(256) + 4*512 + 2*4096
#define ZGT_N 69888     // u32s: 3*GP*GTS ushorts / 2

typedef __attribute__((ext_vector_type(8))) short bf16x8;
typedef __attribute__((ext_vector_type(4))) float f32x4;
typedef __attribute__((ext_vector_type(8))) unsigned short u16x8;

// ---------------- helpers ----------------
__device__ __forceinline__ float wave_sum(float v) {
#pragma unroll
  for (int o = 32; o > 0; o >>= 1) v += __shfl_xor(v, o, 64);
  return v;
}
__device__ __forceinline__ float wave_max(float v) {
#pragma unroll
  for (int o = 32; o > 0; o >>= 1) v = fmaxf(v, __shfl_xor(v, o, 64));
  return v;
}
__device__ __forceinline__ unsigned short f2bf(float x) {  // RNE
  union { float f; unsigned u; } v; v.f = x;
  unsigned r = v.u + 0x7FFFu + ((v.u >> 16) & 1u);
  return (unsigned short)(r >> 16);
}

// ---------------- fused prep: zero-init + [0..127] conv1 dual projection; [128..255] xn/xnR/xnB; all: Wl1T ----------------
__global__ __launch_bounds__(256) void k_prep(const float* __restrict__ x,
                                              const float* __restrict__ W1r,
                                              const float* __restrict__ W1root,
                                              const float* __restrict__ Wl1,
                                              unsigned short* __restrict__ mB,
                                              float* __restrict__ rootb,
                                              float* __restrict__ xn,
                                              unsigned short* __restrict__ xnR,
                                              unsigned short* __restrict__ xnB,
                                              unsigned short* __restrict__ Wl1T,
                                              float* __restrict__ zstats,
                                              unsigned int* __restrict__ zgt) {
  __shared__ float sX[32][132];
  __shared__ unsigned short sT[32][34];
  __shared__ unsigned short sT2[FF][34];
  const int tid = threadIdx.x;
  {
    const int gidx = blockIdx.x * 256 + tid;
    if (gidx < ZSTATS_N) zstats[gidx] = 0.f;
    for (int i = gidx; i < ZGT_N; i += 65536) zgt[i] = 0u;
    if (gidx < GP * DP) {
      const int c = gidx / DP, k = gidx - c * DP;
      Wl1T[gidx] = (c < CC && k < DD) ? f2bf(Wl1[(size_t)k * CC + c]) : (unsigned short)0;
    }
  }
  if (blockIdx.x < 128) {
    const int kb = blockIdx.x;
    for (int p = tid; p < 1024; p += 256) {
      const int node = p >> 5, c4 = p & 31;
      const float4 v = *reinterpret_cast<const float4*>(&x[((size_t)(kb * 32 + node)) * FF + c4 * 4]);
      sX[node][c4 * 4 + 0] = v.x; sX[node][c4 * 4 + 1] = v.y;
      sX[node][c4 * 4 + 2] = v.z; sX[node][c4 * 4 + 3] = v.w;
    }
    __syncthreads();
    const int c = tid & 31, g = tid >> 5;
    float a1[4] = {0.f, 0.f, 0.f, 0.f}, a2[4] = {0.f, 0.f, 0.f, 0.f};
    for (int k = 0; k < FF; ++k) {
      const float w1 = W1r[k * HH + c];
      const float w2 = W1root[k * HH + c];
#pragma unroll
      for (int ni = 0; ni < 4; ++ni) {
        const float av = sX[g * 4 + ni][k];
        a1[ni] = fmaf(av, w1, a1[ni]);
        a2[ni] = fmaf(av, w2, a2[ni]);
      }
    }
#pragma unroll
    for (int ni = 0; ni < 4; ++ni) {
      rootb[((size_t)kb * 32 + g * 4 + ni) * HH + c] = a2[ni];
      sT[c][g * 4 + ni] = f2bf(a1[ni]);
    }
    __syncthreads();
    if (tid < 128) {
      const int row = tid >> 2, seg = tid & 3;
      u16x8 v;
#pragma unroll
      for (int j = 0; j < 8; ++j) v[j] = sT[row][seg * 8 + j];
      *reinterpret_cast<u16x8*>(&mB[((size_t)kb * 32 + row) * 32 + seg * 8]) = v;
    }
  } else {
    const int kb = blockIdx.x - 128;
    const int lane = tid & 63;
    const int w = tid >> 6;
#pragma unroll
    for (int i = 0; i < 8; ++i) {
      const int node = w * 8 + i;
      const int row = kb * 32 + node;
      const float v0 = x[(size_t)row * FF + lane];
      const float v1 = x[(size_t)row * FF + 64 + lane];
      const float ss = wave_sum(v0 * v0 + v1 * v1);
      const float n = fmaxf(sqrtf(ss), 1e-8f);
      const float a = v0 / n, b = v1 / n;
      xn[(size_t)row * FF + lane] = a;
      xn[(size_t)row * FF + 64 + lane] = b;
      xnR[(size_t)row * FF + lane] = f2bf(a);
      xnR[(size_t)row * FF + 64 + lane] = f2bf(b);
      sT2[lane][node] = f2bf(a);
      sT2[64 + lane][node] = f2bf(b);
    }
    __syncthreads();
    const int rowc = tid >> 1, seg = (tid & 1) * 16;
    if (rowc < FF) {
      u16x8 a, b;
#pragma unroll
      for (int j = 0; j < 8; ++j) { a[j] = sT2[rowc][seg + j]; b[j] = sT2[rowc][seg + 8 + j]; }
      *reinterpret_cast<u16x8*>(&xnB[((size_t)kb * GP + rowc) * 32 + seg]) = a;
      *reinterpret_cast<u16x8*>(&xnB[((size_t)kb * GP + rowc) * 32 + seg + 8]) = b;
    }
  }
}

// ---------------- FUSED conv1 (full-K, double-buffered): cvt + adj_t + adj^2 + MFMA + epilogue ----------------
// grid 256; 512 threads; block = 16 rows; 8 chunks of 512 k-cols
__global__ __launch_bounds__(512) void k_conv1(const float* __restrict__ adj,
                                               unsigned short* __restrict__ adj_t,
                                               const unsigned short* __restrict__ mB,
                                               const float* __restrict__ bias,
                                               const float* __restrict__ root,
                                               float* __restrict__ t,
                                               float* __restrict__ colsum,
                                               float* __restrict__ colsq,
                                               float* __restrict__ scalars) {
  __shared__ unsigned short sA[16][520];
  __shared__ float sRed[8][16][33];
  __shared__ float ls[HH], lq[HH];
  __shared__ float redsq[8];
  const int tid = threadIdx.x;
  const int lane = tid & 63;
  const int w = tid >> 6;
  const int l15 = lane & 15;
  const int kgrp = (lane >> 4) * 8;
  const int rb = blockIdx.x;
  const int row0 = rb * 16;
  float adjsq = 0.f;
  f32x4 acc0 = {0.f, 0.f, 0.f, 0.f}, acc1 = {0.f, 0.f, 0.f, 0.f};
  const int fr[4] = {(0 * 512 + tid) >> 7, (1 * 512 + tid) >> 7, (2 * 512 + tid) >> 7,
                     (3 * 512 + tid) >> 7};
  const int fc[4] = {(0 * 512 + tid) & 127, (1 * 512 + tid) & 127, (2 * 512 + tid) & 127,
                     (3 * 512 + tid) & 127};
  float4 v[4];
#pragma unroll
  for (int i = 0; i < 4; ++i)
    v[i] = *reinterpret_cast<const float4*>(&adj[(size_t)(row0 + fr[i]) * NN + fc[i] * 4]);
  for (int chunk = 0; chunk < 8; ++chunk) {
    const int kbase = chunk * 512;
#pragma unroll
    for (int i = 0; i < 4; ++i) {
      const float4 vv = v[i];
      adjsq += vv.x * vv.x + vv.y * vv.y + vv.z * vv.z + vv.w * vv.w;
      ushort4 h;
      h.x = f2bf(vv.x); h.y = f2bf(vv.y); h.z = f2bf(vv.z); h.w = f2bf(vv.w);
      const size_t toff = ((size_t)rb * (NN / 32) + (kbase >> 5) + (fc[i] >> 3)) * 512 +
                          fr[i] * 32 + (fc[i] & 7) * 4;
      *reinterpret_cast<ushort4*>(&adj_t[toff]) = h;
      *reinterpret_cast<ushort4*>(&sA[fr[i]][fc[i] * 4]) = h;
    }
    __syncthreads();
    if (chunk < 7) {
      const int kn = kbase + 512;
#pragma unroll
      for (int i = 0; i < 4; ++i)
        v[i] = *reinterpret_cast<const float4*>(&adj[(size_t)(row0 + fr[i]) * NN + kn + fc[i] * 4]);
    }
#pragma unroll
    for (int j = 0; j < 2; ++j) {
      const int ktl = w * 2 + j;
      const bf16x8 a = *reinterpret_cast<const bf16x8*>(&sA[l15][ktl * 32 + kgrp]);
      const size_t boff = (size_t)(chunk * 16 + ktl) * 1024;
      const bf16x8 b0 = *reinterpret_cast<const bf16x8*>(&mB[boff + l15 * 32 + kgrp]);
      const bf16x8 b1v = *reinterpret_cast<const bf16x8*>(&mB[boff + (16 + l15) * 32 + kgrp]);
      acc0 = __builtin_amdgcn_mfma_f32_16x16x32_bf16(a, b0, acc0, 0, 0, 0);
      acc1 = __builtin_amdgcn_mfma_f32_16x16x32_bf16(a, b1v, acc1, 0, 0, 0);
    }
    __syncthreads();
  }
  const int crow = (lane >> 4) * 4;
#pragma unroll
  for (int r = 0; r < 4; ++r) {
    sRed[w][crow + r][l15] = acc0[r];
    sRed[w][crow + r][16 + l15] = acc1[r];
  }
  if (tid < HH) { ls[tid] = 0.f; lq[tid] = 0.f; }
  adjsq = wave_sum(adjsq);
  if (lane == 0) redsq[w] = adjsq;
  __syncthreads();
  {
    const int r = tid >> 5, c = tid & 31;
    float vv = 0.f;
#pragma unroll
    for (int i = 0; i < 8; ++i) vv += sRed[i][r][c];
    const int n = row0 + r;
    float s = bias[c] + root[(size_t)n * HH + c] + vv;
    s = fmaxf(s, 0.f);
    t[(size_t)n * HH + c] = s;
    atomicAdd(&ls[c], s);
    atomicAdd(&lq[c], s * s);
  }
  __syncthreads();
  if (tid < HH) {
    atomicAdd(&colsum[tid * 16], ls[tid]);
    atomicAdd(&colsq[tid * 16], lq[tid]);
  }
  if (tid == 0) {
    float s = 0.f;
#pragma unroll
    for (int i = 0; i < 8; ++i) s += redsq[i];
    atomicAdd(&scalars[SC(1)], s);
  }
}

// ---------------- FUSED conv2 (full-K): adj_t @ mB + epilogue ----------------
__global__ __launch_bounds__(512) void k_conv2(const unsigned short* __restrict__ adj_t,
                                               const unsigned short* __restrict__ mB,
                                               const float* __restrict__ bias,
                                               const float* __restrict__ root,
                                               float* __restrict__ t,
                                               float* __restrict__ colsum,
                                               float* __restrict__ colsq) {
  __shared__ float sRed[8][16][33];
  __shared__ float ls[HH], lq[HH];
  const int tid = threadIdx.x;
  const int lane = tid & 63;
  const int w = tid >> 6;
  const int l15 = lane & 15;
  const int kgrp = (lane >> 4) * 8;
  const int rb = blockIdx.x;
  const int row0 = rb * 16;
  const int kb0 = w * 16;
  f32x4 acc0 = {0.f, 0.f, 0.f, 0.f}, acc1 = {0.f, 0.f, 0.f, 0.f};
#pragma unroll
  for (int h = 0; h < 2; ++h) {
    bf16x8 a[8], b0[8], b1v[8];
#pragma unroll
    for (int kt = 0; kt < 8; ++kt) {
      const int kb = kb0 + h * 8 + kt;
      const size_t aoff = ((size_t)rb * (NN / 32) + kb) * 512;
      const size_t boff = (size_t)kb * 1024;
      a[kt] = *reinterpret_cast<const bf16x8*>(&adj_t[aoff + l15 * 32 + kgrp]);
      b0[kt] = *reinterpret_cast<const bf16x8*>(&mB[boff + (size_t)l15 * 32 + kgrp]);
      b1v[kt] = *reinterpret_cast<const bf16x8*>(&mB[boff + (size_t)(16 + l15) * 32 + kgrp]);
    }
#pragma unroll
    for (int kt = 0; kt < 8; ++kt) {
      acc0 = __builtin_amdgcn_mfma_f32_16x16x32_bf16(a[kt], b0[kt], acc0, 0, 0, 0);
      acc1 = __builtin_amdgcn_mfma_f32_16x16x32_bf16(a[kt], b1v[kt], acc1, 0, 0, 0);
    }
  }
  const int crow = (lane >> 4) * 4;
#pragma unroll
  for (int r = 0; r < 4; ++r) {
    sRed[w][crow + r][l15] = acc0[r];
    sRed[w][crow + r][16 + l15] = acc1[r];
  }
  if (tid < HH) { ls[tid] = 0.f; lq[tid] = 0.f; }
  __syncthreads();
  {
    const int r = tid >> 5, c = tid & 31;
    float v = 0.f;
#pragma unroll
    for (int i = 0; i < 8; ++i) v += sRed[i][r][c];
    const int n = row0 + r;
    float s = bias[c] + root[(size_t)n * HH + c] + v;
    s = fmaxf(s, 0.f);
    t[(size_t)n * HH + c] = s;
    atomicAdd(&ls[c], s);
    atomicAdd(&lq[c], s * s);
  }
  __syncthreads();
  if (tid < HH) {
    atomicAdd(&colsum[tid * 16], ls[tid]);
    atomicAdd(&colsq[tid * 16], lq[tid]);
  }
}

// ---------------- FUSED conv3 (full-K): adj_t @ x2B, then W3 GEMM epilogue + stats ----------------
__global__ __launch_bounds__(512) void k_conv3(const unsigned short* __restrict__ adj_t,
                                               const unsigned short* __restrict__ x2B,
                                               const float* __restrict__ W3r,
                                               const float* __restrict__ b3,
                                               const float* __restrict__ x2,
                                               const float* __restrict__ W3root,
                                               float* __restrict__ t3,
                                               float* __restrict__ colsum,
                                               float* __restrict__ colsq) {
  __shared__ float sRed[8][16][33];
  __shared__ float sZ[16][33];
  __shared__ float sXr[16][33];
  const int tid = threadIdx.x;
  const int lane = tid & 63;
  const int w = tid >> 6;
  const int l15 = lane & 15;
  const int kgrp = (lane >> 4) * 8;
  const int rb = blockIdx.x;
  const int row0 = rb * 16;
  const int kb0 = w * 16;
  f32x4 acc0 = {0.f, 0.f, 0.f, 0.f}, acc1 = {0.f, 0.f, 0.f, 0.f};
#pragma unroll
  for (int h = 0; h < 2; ++h) {
    bf16x8 a[8], b0[8], b1v[8];
#pragma unroll
    for (int kt = 0; kt < 8; ++kt) {
      const int kb = kb0 + h * 8 + kt;
      const size_t aoff = ((size_t)rb * (NN / 32) + kb) * 512;
      const size_t boff = (size_t)kb * 1024;
      a[kt] = *reinterpret_cast<const bf16x8*>(&adj_t[aoff + l15 * 32 + kgrp]);
      b0[kt] = *reinterpret_cast<const bf16x8*>(&x2B[boff + (size_t)l15 * 32 + kgrp]);
      b1v[kt] = *reinterpret_cast<const bf16x8*>(&x2B[boff + (size_t)(16 + l15) * 32 + kgrp]);
    }
#pragma unroll
    for (int kt = 0; kt < 8; ++kt) {
      acc0 = __builtin_amdgcn_mfma_f32_16x16x32_bf16(a[kt], b0[kt], acc0, 0, 0, 0);
      acc1 = __builtin_amdgcn_mfma_f32_16x16x32_bf16(a[kt], b1v[kt], acc1, 0, 0, 0);
    }
  }
  const int crow = (lane >> 4) * 4;
#pragma unroll
  for (int r = 0; r < 4; ++r) {
    sRed[w][crow + r][l15] = acc0[r];
    sRed[w][crow + r][16 + l15] = acc1[r];
  }
  {
    const int r = tid >> 5, c = tid & 31;
    if (tid < 512) sXr[r][c] = x2[(size_t)(row0 + r) * HH + c];
  }
  __syncthreads();
  {
    const int r = tid >> 5, c = tid & 31;
    float v = 0.f;
#pragma unroll
    for (int i = 0; i < 8; ++i) v += sRed[i][r][c];
    sZ[r][c] = v;
  }
  __syncthreads();
  const int c = tid;
  if (c >= CC) return;
  float acc[16];
  const float bb = b3[c];
#pragma unroll
  for (int r = 0; r < 16; ++r) acc[r] = bb;
  for (int k = 0; k < 32; ++k) {
    const float w1 = W3r[k * CC + c];
    const float w2 = W3root[k * CC + c];
#pragma unroll
    for (int r = 0; r < 16; ++r) acc[r] += sZ[r][k] * w1 + sXr[r][k] * w2;
  }
  float lsm = 0.f, lqm = 0.f;
#pragma unroll
  for (int r = 0; r < 16; ++r) {
    const float v = fmaxf(acc[r], 0.f);
    t3[(size_t)(row0 + r) * CC + c] = v;
    lsm += v;
    lqm += v * v;
  }
  atomicAdd(&colsum[c * 16], lsm);
  atomicAdd(&colsq[c * 16], lqm);
}

// ---------------- FUSED: BN1 apply + emb write + conv2 dual projection ----------------
__global__ __launch_bounds__(256) void k_bnproj(const float* __restrict__ t,
                                                const float* __restrict__ colsum,
                                                const float* __restrict__ colsq,
                                                const float* __restrict__ g,
                                                const float* __restrict__ be,
                                                const float* __restrict__ W2r,
                                                const float* __restrict__ W2root,
                                                unsigned short* __restrict__ mB,
                                                float* __restrict__ rootb,
                                                float* __restrict__ emb) {
  __shared__ float sXf[32][33];
  __shared__ unsigned short sT[32][34];
  const int tid = threadIdx.x;
  const int kb = blockIdx.x;
  const int c = tid & 31, gq = tid >> 5;
  const float m = colsum[c * 16] * (1.f / NN);
  const float var = fmaxf(colsq[c * 16] * (1.f / NN) - m * m, 0.f);
  const float Ac = g[c] / sqrtf(var + 1e-5f);
  const float Bc = be[c] - m * Ac;
#pragma unroll
  for (int ni = 0; ni < 4; ++ni) {
    const int n = kb * 32 + gq * 4 + ni;
    const float v = fmaf(Ac, t[(size_t)n * HH + c], Bc);
    emb[(size_t)n * DD + c] = v;
    sXf[gq * 4 + ni][c] = v;
  }
  __syncthreads();
  float a1[4] = {0.f, 0.f, 0.f, 0.f}, a2[4] = {0.f, 0.f, 0.f, 0.f};
  for (int k = 0; k < HH; ++k) {
    const float w1 = W2r[k * HH + c];
    const float w2 = W2root[k * HH + c];
#pragma unroll
    for (int ni = 0; ni < 4; ++ni) {
      const float av = sXf[gq * 4 + ni][k];
      a1[ni] = fmaf(av, w1, a1[ni]);
      a2[ni] = fmaf(av, w2, a2[ni]);
    }
  }
#pragma unroll
  for (int ni = 0; ni < 4; ++ni) {
    rootb[((size_t)kb * 32 + gq * 4 + ni) * HH + c] = a2[ni];
    sT[c][gq * 4 + ni] = f2bf(a1[ni]);
  }
  __syncthreads();
  if (tid < 128) {
    const int row = tid >> 2, seg = tid & 3;
    u16x8 v;
#pragma unroll
    for (int j = 0; j < 8; ++j) v[j] = sT[row][seg * 8 + j];
    *reinterpret_cast<u16x8*>(&mB[((size_t)kb * 32 + row) * 32 + seg * 8]) = v;
  }
}

// ---------------- bn apply conv2 + x2 + emb + tiled x2B ----------------
__global__ __launch_bounds__(256) void k_bnapply32(const float* __restrict__ t,
                                                   const float* __restrict__ colsum,
                                                   const float* __restrict__ colsq,
                                                   const float* __restrict__ g,
                                                   const float* __restrict__ be,
                                                   float* __restrict__ xo,
                                                   float* __restrict__ emb, int embOff,
                                                   unsigned short* __restrict__ xB) {
  __shared__ unsigned short sT[32][34];
  const int tid = threadIdx.x;
  const int kb = blockIdx.x;
  const int c = tid & 31, gq = tid >> 5;
  const float m = colsum[c * 16] * (1.f / NN);
  const float var = fmaxf(colsq[c * 16] * (1.f / NN) - m * m, 0.f);
  const float Ac = g[c] / sqrtf(var + 1e-5f);
  const float Bc = be[c] - m * Ac;
#pragma unroll
  for (int ni = 0; ni < 4; ++ni) {
    const int n = kb * 32 + gq * 4 + ni;
    const float v = fmaf(Ac, t[(size_t)n * HH + c], Bc);
    xo[(size_t)n * HH + c] = v;
    emb[(size_t)n * DD + embOff + c] = v;
    sT[c][gq * 4 + ni] = f2bf(v);
  }
  __syncthreads();
  if (tid < 128) {
    const int row = tid >> 2, seg = tid & 3;
    u16x8 o;
#pragma unroll
    for (int j = 0; j < 8; ++j) o[j] = sT[row][seg * 8 + j];
    *reinterpret_cast<u16x8*>(&xB[((size_t)kb * 32 + row) * 32 + seg * 8]) = o;
  }
}

// ---------------- fused head: BN3 inline + emb write + MFMA logits + softmax ----------------
__global__ __launch_bounds__(256) void k_head(float* __restrict__ emb,
                                              const float* __restrict__ t3,
                                              const float* __restrict__ colsum3,
                                              const float* __restrict__ colsq3,
                                              const float* __restrict__ g3,
                                              const float* __restrict__ be3,
                                              const unsigned short* __restrict__ Wl1T,
                                              const float* __restrict__ bl1,
                                              float* __restrict__ s1,
                                              float* __restrict__ sn,
                                              unsigned short* __restrict__ s1B,
                                              unsigned short* __restrict__ snB,
                                              unsigned short* __restrict__ snR,
                                              float* __restrict__ scalars) {
  __shared__ unsigned short sA[16][296];
  __shared__ float lg[16][212];
  __shared__ unsigned short sTa[16][212];
  __shared__ unsigned short sTb[16][212];
  __shared__ float redE[4];
  const int tid = threadIdx.x;
  const int row0 = blockIdx.x * 16;
  for (int p = tid; p < 16 * 36; p += 256) {
    const int r = p / 36, ch = p - r * 36;
    const int row = row0 + r;
#pragma unroll
    for (int j = 0; j < 8; ++j) {
      const int d = ch * 8 + j;
      float v;
      if (d < 2 * HH) {
        v = emb[(size_t)row * DD + d];
      } else if (d < DD) {
        const int c3 = d - 2 * HH;
        const float m = colsum3[c3 * 16] * (1.f / NN);
        const float var = fmaxf(colsq3[c3 * 16] * (1.f / NN) - m * m, 0.f);
        const float Ac = g3[c3] / sqrtf(var + 1e-5f);
        const float Bc = be3[c3] - m * Ac;
        v = fmaf(Ac, t3[(size_t)row * CC + c3], Bc);
        emb[(size_t)row * DD + d] = v;
      } else {
        v = 0.f;
      }
      sA[r][d] = f2bf(v);
    }
  }
  __syncthreads();
  const int lane = tid & 63;
  const int w = tid >> 6;
  const int l15 = lane & 15;
  const int kgrp = (lane >> 4) * 8;
  {
    f32x4 acc[4];
#pragma unroll
    for (int i = 0; i < 4; ++i) acc[i] = (f32x4){0.f, 0.f, 0.f, 0.f};
#pragma unroll
    for (int i = 0; i < 4; ++i) {
      const int ct = w + i * 4;
      if (ct < 13) {
        const size_t brow = (size_t)(ct * 16 + l15) * DP;
#pragma unroll
        for (int k0 = 0; k0 < DP; k0 += 32) {
          const bf16x8 a = *reinterpret_cast<const bf16x8*>(&sA[l15][k0 + kgrp]);
          const bf16x8 b = *reinterpret_cast<const bf16x8*>(&Wl1T[brow + k0 + kgrp]);
          acc[i] = __builtin_amdgcn_mfma_f32_16x16x32_bf16(a, b, acc[i], 0, 0, 0);
        }
      }
    }
    const int lrow = (lane >> 4) * 4;
#pragma unroll
    for (int i = 0; i < 4; ++i) {
      const int ct = w + i * 4;
      if (ct < 13) {
#pragma unroll
        for (int r = 0; r < 4; ++r) lg[lrow + r][ct * 16 + l15] = acc[i][r];
      }
    }
  }
  __syncthreads();
  const int r0 = w * 4;
  const int c0 = lane * 4;
  const bool active = (c0 < GP);
  float bl[4];
#pragma unroll
  for (int j = 0; j < 4; ++j) bl[j] = (c0 + j < CC) ? bl1[c0 + j] : 0.f;
  float ent_acc = 0.f;
#pragma unroll
  for (int r = 0; r < 4; ++r) {
    const int lr = r0 + r;
    const int row = row0 + lr;
    float lgv[4] = {0.f, 0.f, 0.f, 0.f};
    if (active) {
#pragma unroll
      for (int j = 0; j < 4; ++j) lgv[j] = lg[lr][c0 + j];
    }
    float v[4];
    float ml = -1e30f;
#pragma unroll
    for (int j = 0; j < 4; ++j) {
      const int c = c0 + j;
      v[j] = (c < CC) ? fmaxf(lgv[j] + bl[j], 0.f) : -1e30f;
      ml = fmaxf(ml, v[j]);
    }
    const float m = wave_max(ml);
    float e[4];
    float sl = 0.f;
#pragma unroll
    for (int j = 0; j < 4; ++j) {
      const int c = c0 + j;
      e[j] = (c < CC) ? __expf(v[j] - m) : 0.f;
      sl += e[j];
    }
    const float S = wave_sum(sl);
    const float invS = 1.f / S;
    float p[4];
    float ql = 0.f;
#pragma unroll
    for (int j = 0; j < 4; ++j) {
      p[j] = e[j] * invS;
      ql += p[j] * p[j];
    }
    const float q = wave_sum(ql);
    const float inv = 1.f / fmaxf(sqrtf(q), 1e-8f);
    float m2l = -1e30f;
#pragma unroll
    for (int j = 0; j < 4; ++j) {
      const int c = c0 + j;
      if (c < CC) {
        s1[(size_t)row * CC + c] = p[j];
        sn[(size_t)row * CC + c] = p[j] * inv;
        m2l = fmaxf(m2l, p[j]);
      }
    }
    if (active) {
#pragma unroll
      for (int j = 0; j < 4; ++j) {
        const int c = c0 + j;
        const bool ok = (c < CC);
        sTa[lr][c] = ok ? f2bf(p[j]) : (unsigned short)0;
        sTb[lr][c] = ok ? f2bf(p[j] * inv) : (unsigned short)0;
      }
    }
    if (c0 < GTS) {
      ushort4 o;
      o.x = (c0 + 0 < CC) ? f2bf(p[0] * inv) : (unsigned short)0;
      o.y = (c0 + 1 < CC) ? f2bf(p[1] * inv) : (unsigned short)0;
      o.z = (c0 + 2 < CC) ? f2bf(p[2] * inv) : (unsigned short)0;
      o.w = (c0 + 3 < CC) ? f2bf(p[3] * inv) : (unsigned short)0;
      *reinterpret_cast<ushort4*>(&snR[(size_t)row * GTS + c0]) = o;
    }
    const float m2 = wave_max(m2l);
    float e2[4];
    float s2l = 0.f;
#pragma unroll
    for (int j = 0; j < 4; ++j) {
      const int c = c0 + j;
      e2[j] = (c < CC) ? __expf(p[j] - m2) : 0.f;
      s2l += e2[j];
    }
    const float S2 = wave_sum(s2l);
    const float invS2 = 1.f / S2;
    float tl = 0.f;
#pragma unroll
    for (int j = 0; j < 4; ++j) {
      const int c = c0 + j;
      if (c < CC) {
        const float sp = e2[j] * invS2;
        tl -= sp * logf(sp + 1e-15f);
      }
    }
    ent_acc += tl;
  }
  ent_acc = wave_sum(ent_acc);
  if (lane == 0) redE[w] = ent_acc;
  __syncthreads();
  if (tid == 0) atomicAdd(&scalars[SC(2)], redE[0] + redE[1] + redE[2] + redE[3]);
  if (tid < GP) {
    const int kb = row0 >> 5, no = row0 & 31;
    u16x8 oa0, ob0, oa1, ob1;
#pragma unroll
    for (int r = 0; r < 8; ++r) {
      oa0[r] = sTa[r][tid]; ob0[r] = sTb[r][tid];
      oa1[r] = sTa[8 + r][tid]; ob1[r] = sTb[8 + r][tid];
    }
    *reinterpret_cast<u16x8*>(&s1B[((size_t)kb * GP + tid) * 32 + no]) = oa0;
    *reinterpret_cast<u16x8*>(&s1B[((size_t)kb * GP + tid) * 32 + no + 8]) = oa1;
    *reinterpret_cast<u16x8*>(&snB[((size_t)kb * GP + tid) * 32 + no]) = ob0;
    *reinterpret_cast<u16x8*>(&snB[((size_t)kb * GP + tid) * 32 + no + 8]) = ob1;
  }
}

// ---------------- merged tail: [0..511] norm pass; [512..1187] Grams ----------------
__global__ __launch_bounds__(512) void k_tail(const unsigned short* __restrict__ adj_t,
                                              const unsigned short* __restrict__ s1B,
                                              const float* __restrict__ s1,
                                              const unsigned short* __restrict__ xnB,
                                              const unsigned short* __restrict__ snB,
                                              unsigned short* __restrict__ GT0,
                                              unsigned short* __restrict__ GxsT,
                                              unsigned short* __restrict__ GsT,
                                              float* __restrict__ scalars) {
  const int tid = threadIdx.x;
  const int lane = tid & 63;
  const int w = tid >> 6;
  const int l15 = lane & 15;
  const int kgrp = (lane >> 4) * 8;
  if (blockIdx.x < 512) {
    __shared__ unsigned short sB[2][13][16][BST];
    __shared__ float red[8];
    const int bx = blockIdx.x & 31;
    const int ky = blockIdx.x >> 5;
    const int rb = bx * 8 + w;
    const int kb0 = ky * 8;
    const int g = lane >> 4;
    const int p0 = tid;
    const int ct0 = p0 >> 6, rr0 = (p0 >> 2) & 15, sg0 = (p0 & 3) * 8;
    const int p1 = tid + 512;
    const bool v1 = (p1 < 832);
    const int ct1 = p1 >> 6, rr1 = (p1 >> 2) & 15, sg1 = (p1 & 3) * 8;
    f32x4 acc[13];
#pragma unroll
    for (int ct = 0; ct < 13; ++ct) acc[ct] = (f32x4){0.f, 0.f, 0.f, 0.f};
    u16x8 st0, st1;
    st0 = *reinterpret_cast<const u16x8*>(&s1B[((size_t)kb0 * GP + ct0 * 16 + rr0) * 32 + sg0]);
    if (v1) st1 = *reinterpret_cast<const u16x8*>(&s1B[((size_t)kb0 * GP + ct1 * 16 + rr1) * 32 + sg1]);
    *reinterpret_cast<u16x8*>(&sB[0][ct0][rr0][sg0]) = st0;
    if (v1) *reinterpret_cast<u16x8*>(&sB[0][ct1][rr1][sg1]) = st1;
    __syncthreads();
    bf16x8 a = *reinterpret_cast<const bf16x8*>(
        &adj_t[((size_t)rb * (NN / 32) + kb0) * 512 + l15 * 32 + kgrp]);
    for (int kt = 0; kt < 8; ++kt) {
      const int cur = kt & 1;
      if (kt < 7) {
        const size_t kb = kb0 + kt + 1;
        st0 = *reinterpret_cast<const u16x8*>(&s1B[(kb * GP + ct0 * 16 + rr0) * 32 + sg0]);
        if (v1) st1 = *reinterpret_cast<const u16x8*>(&s1B[(kb * GP + ct1 * 16 + rr1) * 32 + sg1]);
      }
      bf16x8 a_next = a;
      if (kt < 7)
        a_next = *reinterpret_cast<const bf16x8*>(
            &adj_t[((size_t)rb * (NN / 32) + kb0 + kt + 1) * 512 + l15 * 32 + kgrp]);
#pragma unroll
      for (int ct = 0; ct < 13; ++ct) {
        const bf16x8 b = *reinterpret_cast<const bf16x8*>(&sB[cur][ct][l15][kgrp]);
        acc[ct] = __builtin_amdgcn_mfma_f32_16x16x32_bf16(a, b, acc[ct], 0, 0, 0);
      }
      if (kt < 7) {
        *reinterpret_cast<u16x8*>(&sB[cur ^ 1][ct0][rr0][sg0]) = st0;
        if (v1) *reinterpret_cast<u16x8*>(&sB[cur ^ 1][ct1][rr1][sg1]) = st1;
      }
      __syncthreads();
      a = a_next;
    }
    const int rout = rb * 16 + g * 4;
    float sc = 0.f;
#pragma unroll
    for (int ct = 0; ct < 13; ++ct) {
      const int col = ct * 16 + l15;
      if (col < CC) {
#pragma unroll
        for (int r = 0; r < 4; ++r)
          sc = fmaf(acc[ct][r], s1[(size_t)(rout + r) * CC + col], sc);
      }
    }
    sc = wave_sum(sc);
    if (lane == 0) red[w] = sc;
    __syncthreads();
    if (tid == 0) {
      float s = 0.f;
#pragma unroll
      for (int i = 0; i < 8; ++i) s += red[i];
      atomicAdd(&scalars[SC(0)], s);
    }
  } else {
    __shared__ float redg[8][16][17];
    __shared__ float redq[8];
    const int gb = blockIdx.x - 512;
    const int gid = gb / 169;
    const int rem = gb - gid * 169;
    const int tp = (rem % 13) * 16;
    const int tq = (rem / 13) * 16;
    const unsigned short *PT, *QT;
    unsigned short* GTout = nullptr;
    if (gid == 0)      { PT = xnB; QT = xnB; GTout = GT0;  if (tp >= FF || tq >= FF) return; }
    else if (gid == 1) { PT = xnB; QT = snB; GTout = GxsT; if (tp >= FF) return; }
    else if (gid == 2) { PT = snB; QT = snB; GTout = GsT; }
    else               { PT = s1B; QT = s1B; }
    f32x4 acc = {0.f, 0.f, 0.f, 0.f};
#pragma unroll 4
    for (int kt = 0; kt < 16; ++kt) {
      const int kb = w * 16 + kt;
      const bf16x8 a = *reinterpret_cast<const bf16x8*>(&PT[((size_t)kb * GP + tp + l15) * 32 + kgrp]);
      const bf16x8 b = *reinterpret_cast<const bf16x8*>(&QT[((size_t)kb * GP + tq + l15) * 32 + kgrp]);
      acc = __builtin_amdgcn_mfma_f32_16x16x32_bf16(a, b, acc, 0, 0, 0);
    }
    const int crow = (lane >> 4) * 4;
#pragma unroll
    for (int r = 0; r < 4; ++r) redg[w][crow + r][l15] = acc[r];
    __syncthreads();
    const int rr = tid >> 4, cc = tid & 15;
    if (gid == 3) {
      float q = 0.f;
      if (tid < 256) {
        float v = 0.f;
#pragma unroll
        for (int i = 0; i < 8; ++i) v += redg[i][rr][cc];
        q = v * v;
      }
      q = wave_sum(q);
      if (lane == 0) redq[w] = q;
      __syncthreads();
      if (tid == 0) {
        float s = 0.f;
#pragma unroll
        for (int i = 0; i < 8; ++i) s += redq[i];
        atomicAdd(&scalars[SC(5)], s);
      }
    } else {
      if (tid < 256) {
        float vt = 0.f;
#pragma unroll
        for (int i = 0; i < 8; ++i) vt += redg[i][cc][rr];
        GTout[(size_t)(tq + rr) * GTS + (tp + cc)] = f2bf(vt);
      }
    }
  }
}

// ---------------- merged final losses: [0..255] rowsim; [256..767] teams; ticket finalize ----------------
__global__ __launch_bounds__(256) void k_finloss(const unsigned short* __restrict__ xnR,
                                                 const unsigned short* __restrict__ snR,
                                                 const unsigned short* __restrict__ GT0,
                                                 const unsigned short* __restrict__ GxsT,
                                                 const unsigned short* __restrict__ GsT,
                                                 const float* __restrict__ xn,
                                                 const float* __restrict__ sn,
                                                 const float* __restrict__ emb,
                                                 const int* __restrict__ teams,
                                                 const int* __restrict__ reps,
                                                 float* __restrict__ scalars,
                                                 unsigned int* __restrict__ ticket,
                                                 float* __restrict__ outsc) {
  __shared__ __align__(16) char smem[47424];
  const int tid = threadIdx.x;
  if (blockIdx.x < 256) {
    unsigned short (*sX)[136] = (unsigned short(*)[136])(smem);
    unsigned short (*sS)[232] = (unsigned short(*)[232])(smem + 4352);
    float (*sH1)[132] = (float(*)[132])(smem + 11776);
    float (*sU)[212] = (float(*)[212])(smem + 20224);
    float (*sH2)[212] = (float(*)[212])(smem + 33792);
    float* redb = (float*)(smem + 47360);
    const int row0 = blockIdx.x * 16;
    for (int p = tid; p < 16 * 16; p += 256) {
      const int r = p >> 4, ch = p & 15;
      *reinterpret_cast<u16x8*>(&sX[r][ch * 8]) =
          *reinterpret_cast<const u16x8*>(&xnR[(size_t)(row0 + r) * FF + ch * 8]);
    }
    for (int p = tid; p < 16 * 28; p += 256) {
      const int r = p / 28, ch = p - r * 28;
      *reinterpret_cast<u16x8*>(&sS[r][ch * 8]) =
          *reinterpret_cast<const u16x8*>(&snR[(size_t)(row0 + r) * GTS + ch * 8]);
    }
    __syncthreads();
    const int lane = tid & 63;
    const int w = tid >> 6;
    const int l15 = lane & 15;
    const int kgrp = (lane >> 4) * 8;
    const int lrow = (lane >> 4) * 4;
#pragma unroll
    for (int i = 0; i < 2; ++i) {
      const int ct = w + i * 4;
      f32x4 acc = {0.f, 0.f, 0.f, 0.f};
      const size_t brow = (size_t)(ct * 16 + l15) * GTS;
#pragma unroll
      for (int k0 = 0; k0 < FF; k0 += 32) {
        const bf16x8 a = *reinterpret_cast<const bf16x8*>(&sX[l15][k0 + kgrp]);
        const bf16x8 b = *reinterpret_cast<const bf16x8*>(&GT0[brow + k0 + kgrp]);
        acc = __builtin_amdgcn_mfma_f32_16x16x32_bf16(a, b, acc, 0, 0, 0);
      }
#pragma unroll
      for (int r = 0; r < 4; ++r) sH1[lrow + r][ct * 16 + l15] = acc[r];
    }
#pragma unroll
    for (int i = 0; i < 4; ++i) {
      const int ct = w + i * 4;
      if (ct < 13) {
        f32x4 acc = {0.f, 0.f, 0.f, 0.f};
        const size_t brow = (size_t)(ct * 16 + l15) * GTS;
#pragma unroll
        for (int k0 = 0; k0 < FF; k0 += 32) {
          const bf16x8 a = *reinterpret_cast<const bf16x8*>(&sX[l15][k0 + kgrp]);
          const bf16x8 b = *reinterpret_cast<const bf16x8*>(&GxsT[brow + k0 + kgrp]);
          acc = __builtin_amdgcn_mfma_f32_16x16x32_bf16(a, b, acc, 0, 0, 0);
        }
#pragma unroll
        for (int r = 0; r < 4; ++r) sU[lrow + r][ct * 16 + l15] = acc[r];
      }
    }
#pragma unroll
    for (int i = 0; i < 4; ++i) {
      const int ct = w + i * 4;
      if (ct < 13) {
        f32x4 acc = {0.f, 0.f, 0.f, 0.f};
        const size_t brow = (size_t)(ct * 16 + l15) * GTS;
#pragma unroll
        for (int k0 = 0; k0 < GTS; k0 += 32) {
          const bf16x8 a = *reinterpret_cast<const bf16x8*>(&sS[l15][k0 + kgrp]);
          const bf16x8 b = *reinterpret_cast<const bf16x8*>(&GsT[brow + k0 + kgrp]);
          acc = __builtin_amdgcn_mfma_f32_16x16x32_bf16(a, b, acc, 0, 0, 0);
        }
#pragma unroll
        for (int r = 0; r < 4; ++r) sH2[lrow + r][ct * 16 + l15] = acc[r];
      }
    }
    __syncthreads();
    float acc_sim = 0.f;
#pragma unroll
    for (int r = 0; r < 4; ++r) {
      const int lr = w * 4 + r;
      const int row = row0 + lr;
      float suu = 0.f, suv = 0.f, svv = 0.f;
#pragma unroll
      for (int c0 = 0; c0 < FF; c0 += 64) {
        suu = fmaf(xn[(size_t)row * FF + c0 + lane], sH1[lr][c0 + lane], suu);
      }
      for (int cb = lane; cb < CC; cb += 64) {
        const float sv = sn[(size_t)row * CC + cb];
        suv = fmaf(sU[lr][cb], sv, suv);
        svv = fmaf(sH2[lr][cb], sv, svv);
      }
      suu = wave_sum(suu);
      suv = wave_sum(suv);
      svv = wave_sum(svv);
      if (lane == 0) acc_sim += suv / sqrtf(suu * svv);
    }
    if (lane == 0) redb[w] = acc_sim;
    __syncthreads();
    if (tid == 0) atomicAdd(&scalars[SC(3)], redb[0] + redb[1] + redb[2] + redb[3]);
  } else {
    float* red = (float*)smem;
    const int team = blockIdx.x - 256;
    float part = 0.f;
    for (int d = tid; d < DD; d += 256) {
      float a = 0.f, b = 0.f;
#pragma unroll
      for (int m = 0; m < RR; ++m) a += emb[(size_t)reps[team * RR + m] * DD + d];
#pragma unroll
      for (int m = RR; m < TT; ++m) b += emb[(size_t)teams[team * TT + m] * DD + d];
      part += fabsf(a * (1.f / RR) - b * (1.f / (TT - RR)));
    }
    part = wave_sum(part);
    if ((tid & 63) == 0) red[tid >> 6] = part;
    __syncthreads();
    if (tid == 0) atomicAdd(&scalars[SC(4)], red[0] + red[1] + red[2] + red[3]);
  }
  // ticket finalize (last of 768 blocks computes output scalars)
  if (tid == 0) {
    __threadfence();
    const unsigned int old = atomicAdd(ticket, 1u);
    if (old == (unsigned int)(NFIN - 1)) {
      const float trSAS = atomicAdd(&scalars[SC(0)], 0.f);
      const float adjsq = atomicAdd(&scalars[SC(1)], 0.f);
      const float ent   = atomicAdd(&scalars[SC(2)], 0.f);
      const float simS  = atomicAdd(&scalars[SC(3)], 0.f);
      const float embS  = atomicAdd(&scalars[SC(4)], 0.f);
      const float sumP2 = atomicAdd(&scalars[SC(5)], 0.f);
      const float normsq = fmaxf(sumP2 - 2.f * trSAS + adjsq, 0.f);
      const float norm = sqrtf(normsq);
      const float e1 = ent * (1.f / NN);
      const float sim = -simS * (1.f / NN);
      const float embl = embS * (1.f / LL);
      outsc[0] = norm;
      outsc[1] = e1;
      outsc[2] = sim;
      outsc[3] = 100.f * norm + 10.f * e1 + 100.f * sim + embl;
      outsc[4] = embl;
    }
  }
}

// ================= launch =================
extern "C" void kernel_launch(void* const* d_in, const int* in_sizes, int n_in,
                              void* d_out, int out_size, void* d_ws, size_t ws_size,
                              hipStream_t stream) {
  const float* x      = (const float*)d_in[0];
  const float* adj    = (const float*)d_in[1];
  const int*   teams  = (const int*)d_in[2];
  const int*   reps   = (const int*)d_in[3];
  const float* W1r    = (const float*)d_in[4];
  const float* b1     = (const float*)d_in[5];
  const float* W1root = (const float*)d_in[6];
  const float* g1     = (const float*)d_in[7];
  const float* be1    = (const float*)d_in[8];
  const float* W2r    = (const float*)d_in[9];
  const float* b2     = (const float*)d_in[10];
  const float* W2root = (const float*)d_in[11];
  const float* g2     = (const float*)d_in[12];
  const float* be2    = (const float*)d_in[13];
  const float* W3r    = (const float*)d_in[14];
  const float* b3     = (const float*)d_in[15];
  const float* W3root = (const float*)d_in[16];
  const float* g3     = (const float*)d_in[17];
  const float* be3    = (const float*)d_in[18];
  const float* Wl1    = (const float*)d_in[19];
  const float* bl1    = (const float*)d_in[20];

  char* wp = (char*)d_ws;
  auto alloc = [&](size_t bytes) { char* p = wp; wp += (bytes + 255) & ~(size_t)255; return p; };
  unsigned short* adj_t = (unsigned short*)alloc((size_t)NN * NN * 2);
  unsigned short* mB    = (unsigned short*)alloc((size_t)HH * NN * 2);
  unsigned short* x2B   = (unsigned short*)alloc((size_t)HH * NN * 2);
  unsigned short* s1B   = (unsigned short*)alloc((size_t)GP * NN * 2);
  unsigned short* snB   = (unsigned short*)alloc((size_t)GP * NN * 2);
  unsigned short* Wl1T  = (unsigned short*)alloc((size_t)GP * DP * 2);
  unsigned short* xnR   = (unsigned short*)alloc((size_t)NN * FF * 2);
  unsigned short* snR   = (unsigned short*)alloc((size_t)NN * GTS * 2);
  float* rootb  = (float*)alloc((size_t)NN * HH * 4);
  float* t      = (float*)alloc((size_t)NN * HH * 4);
  float* x2     = (float*)alloc((size_t)NN * HH * 4);
  float* t3     = (float*)alloc((size_t)NN * CC * 4);
  float* sn     = (float*)alloc((size_t)NN * CC * 4);
  float* xn     = (float*)alloc((size_t)NN * FF * 4);
  unsigned short* xnB   = (unsigned short*)alloc((size_t)GP * NN * 2);
  // ---- zero-init region (zeroed by k_prep) ----
  float* scalars = (float*)alloc(256 * 4);
  float* colsum1 = (float*)alloc(512 * 4);
  float* colsq1  = (float*)alloc(512 * 4);
  float* colsum2 = (float*)alloc(512 * 4);
  float* colsq2  = (float*)alloc(512 * 4);
  float* colsum3 = (float*)alloc(4096 * 4);
  float* colsq3  = (float*)alloc(4096 * 4);
  unsigned short* GTall = (unsigned short*)alloc((size_t)3 * GP * GTS * 2);
  unsigned short* GT0   = GTall;
  unsigned short* GxsT  = GTall + (size_t)GP * GTS;
  unsigned short* GsT   = GTall + (size_t)2 * GP * GTS;
  unsigned int* ticket = (unsigned int*)&scalars[SC(6)];
  (void)ws_size; (void)in_sizes; (void)n_in; (void)out_size;

  float* out   = (float*)d_out;
  float* s1    = out;                          // N*C
  float* outsc = out + (size_t)NN * CC;        // 5 scalars
  float* emb   = out + (size_t)NN * CC + 5;    // N*D

  // prep: zero-init + conv1 projection + xn/xnR/xnB + Wl1T
  k_prep<<<256, 256, 0, stream>>>(x, W1r, W1root, Wl1, mB, rootb, xn, xnR, xnB, Wl1T,
                                  scalars, (unsigned int*)GTall);

  // conv1 (full-K, double-buffered)
  k_conv1<<<256, 512, 0, stream>>>(adj, adj_t, mB, b1, rootb, t, colsum1, colsq1, scalars);
  k_bnproj<<<NN / 32, 256, 0, stream>>>(t, colsum1, colsq1, g1, be1, W2r, W2root, mB, rootb, emb);

  // conv2 (full-K fused)
  k_conv2<<<256, 512, 0, stream>>>(adj_t, mB, b2, rootb, t, colsum2, colsq2);
  k_bnapply32<<<NN / 32, 256, 0, stream>>>(t, colsum2, colsq2, g2, be2, x2, emb, HH, x2B);

  // conv3 (full-K fused + W3 GEMM epilogue)
  k_conv3<<<256, 512, 0, stream>>>(adj_t, x2B, W3r, b3, x2, W3root, t3, colsum3, colsq3);

  // fused head (BN3 + emb + logits + softmax)
  k_head<<<NN / 16, 256, 0, stream>>>(emb, t3, colsum3, colsq3, g3, be3, Wl1T, bl1,
                                      s1, sn, s1B, snB, snR, scalars);

  // merged tail: norm pass + Grams
  k_tail<<<512 + 676, 512, 0, stream>>>(adj_t, s1B, s1, xnB, snB, GT0, GxsT, GsT, scalars);

  // merged final: rowsim + teams + ticket finalize
  k_finloss<<<NFIN, 256, 0, stream>>>(xnR, snR, GT0, GxsT, GsT, xn, sn, emb, teams, reps,
                                      scalars, ticket, outsc);
}